// Round 1
// baseline (510.685 us; speedup 1.0000x reference)
//
#include <hip/hip_runtime.h>
#include <hip/hip_bf16.h>
#include <stdint.h>

#define NB 4
#define NT 8192
#define ND 1024
#define NH 16
#define NHD 64
#define NK 64        // top-k
#define NM (NB*NT)   // 32768

typedef __attribute__((ext_vector_type(4))) float f32x4;
typedef __attribute__((ext_vector_type(8))) short s16x8;
typedef const void __attribute__((address_space(1)))* gas1_t;
typedef void __attribute__((address_space(3)))* las3_t;

__device__ __forceinline__ float bf2f(ushort u) {
  union { uint32_t i; float f; } v; v.i = ((uint32_t)u) << 16; return v.f;
}
__device__ __forceinline__ ushort f2bf(float f) {
  union { float f; uint32_t i; } v; v.f = f;
  uint32_t r = v.i + 0x7FFFu + ((v.i >> 16) & 1u);
  return (ushort)(r >> 16);
}

// ---- convert the four weight matrices to bf16 ----
__global__ __launch_bounds__(256) void convert_w_kernel(
    const float* __restrict__ Wq, const float* __restrict__ Wk,
    const float* __restrict__ Wv, const float* __restrict__ Wo,
    ushort* __restrict__ wqb, ushort* __restrict__ wkb,
    ushort* __restrict__ wvb, ushort* __restrict__ wob) {
  int i = blockIdx.x * 256 + threadIdx.x;   // grid covers exactly 1M
  wqb[i] = f2bf(Wq[i]); wkb[i] = f2bf(Wk[i]);
  wvb[i] = f2bf(Wv[i]); wob[i] = f2bf(Wo[i]);
}

// ---- u[h][e] = sum_d wscore[d] * Wk[h*64+d][e]  (fp32, exact path for topk) ----
__global__ __launch_bounds__(256) void prep_u_kernel(
    const float* __restrict__ Wk, const float* __restrict__ wscore,
    float* __restrict__ u) {
  int e = (blockIdx.x & 3) * 256 + threadIdx.x;
  int h = blockIdx.x >> 2;
  float acc = 0.f;
  #pragma unroll 8
  for (int d = 0; d < NHD; ++d) acc += wscore[d] * Wk[(size_t)(h*NHD + d)*ND + e];
  u[h*ND + e] = acc;
}

// ---- x -> bf16, and fp32 indexer scores[b*16+h][t] = x_row . u[h] ----
__global__ __launch_bounds__(256) void prep_x_kernel(
    const float* __restrict__ x, const float* __restrict__ u,
    ushort* __restrict__ xb, float* __restrict__ scores) {
  __shared__ float ul[NH*ND];   // 64 KiB
  int t = threadIdx.x;
  {
    const float4* u4 = (const float4*)u;
    float4* l4 = (float4*)ul;
    for (int i = t; i < NH*ND/4; i += 256) l4[i] = u4[i];
  }
  __syncthreads();
  int w = t >> 6, l = t & 63;
  #pragma unroll 1
  for (int rr = 0; rr < 16; ++rr) {
    int row = blockIdx.x * 64 + w * 16 + rr;   // global token row (b*T+t)
    const float4* xr = (const float4*)(x + (size_t)row * ND);
    float4 xv[4];
    #pragma unroll
    for (int j = 0; j < 4; ++j) xv[j] = xr[l + j*64];     // elems l*4 + j*256
    #pragma unroll
    for (int j = 0; j < 4; ++j) {
      ushort4 o;
      o.x = f2bf(xv[j].x); o.y = f2bf(xv[j].y); o.z = f2bf(xv[j].z); o.w = f2bf(xv[j].w);
      *(ushort4*)(xb + (size_t)row * ND + l*4 + j*256) = o;
    }
    int boff = ((row >> 13) << 4);
    int tt = row & (NT - 1);
    #pragma unroll 1
    for (int h = 0; h < NH; ++h) {
      const float4* ur = (const float4*)(ul + h*ND);
      float p = 0.f;
      #pragma unroll
      for (int j = 0; j < 4; ++j) {
        float4 uv = ur[l + j*64];
        p += xv[j].x*uv.x + xv[j].y*uv.y + xv[j].z*uv.z + xv[j].w*uv.w;
      }
      #pragma unroll
      for (int m = 32; m >= 1; m >>= 1) p += __shfl_xor(p, m, 64);
      if (l == 0) scores[(size_t)(boff + h) * NT + tt] = p;
    }
  }
}

// ---- top-64 per (b,h); only the SET matters (softmax+sum is perm-invariant) ----
__global__ __launch_bounds__(256) void topk_kernel(
    const float* __restrict__ scores, int* __restrict__ tidx) {
  int bh = blockIdx.x, t = threadIdx.x;
  __shared__ float sv[NT];     // 32 KiB
  __shared__ float wv[4];
  __shared__ int wi[4];
  {
    const float4* sg = (const float4*)(scores + (size_t)bh * NT);
    float4* s4 = (float4*)sv;
    for (int i = t; i < NT/4; i += 256) s4[i] = sg[i];
  }
  __syncthreads();
  for (int it = 0; it < NK; ++it) {
    float bm = -3.0e38f; int bi = 0;
    for (int i = t; i < NT; i += 256) {
      float v = sv[i];
      if (v > bm) { bm = v; bi = i; }
    }
    #pragma unroll
    for (int m = 32; m >= 1; m >>= 1) {
      float ov = __shfl_xor(bm, m, 64);
      int oi = __shfl_xor(bi, m, 64);
      if (ov > bm || (ov == bm && oi < bi)) { bm = ov; bi = oi; }
    }
    if ((t & 63) == 0) { wv[t >> 6] = bm; wi[t >> 6] = bi; }
    __syncthreads();
    if (t == 0) {
      float fb = wv[0]; int fi = wi[0];
      #pragma unroll
      for (int k = 1; k < 4; ++k)
        if (wv[k] > fb || (wv[k] == fb && wi[k] < fi)) { fb = wv[k]; fi = wi[k]; }
      tidx[bh*NK + it] = fi;
      sv[fi] = -3.0e38f;
    }
    __syncthreads();
  }
}

// ---- project ONLY the 64 selected rows per (b,h) into K_sp[key][d], V^T_sp[d][key] ----
__global__ __launch_bounds__(256) void sparse_kv_kernel(
    const ushort* __restrict__ xb, const ushort* __restrict__ wkb,
    const ushort* __restrict__ wvb, const int* __restrict__ tidx,
    ushort* __restrict__ ksp, ushort* __restrict__ vtsp) {
  int bh = blockIdx.x, gy = blockIdx.y;
  int b = bh >> 4, h = bh & 15;
  int t = threadIdx.x;
  __shared__ __align__(16) ushort xl[16][128];
  __shared__ int kid[16];
  if (t < 16) kid[t] = tidx[bh*NK + gy*16 + t];
  int d = t & 63, kq = t >> 6;      // wave = one kq -> LDS reads broadcast
  float ak[4] = {0.f,0.f,0.f,0.f}, av[4] = {0.f,0.f,0.f,0.f};
  const ushort* wkr = wkb + (size_t)(h*NHD + d) * ND;
  const ushort* wvr = wvb + (size_t)(h*NHD + d) * ND;
  for (int kc = 0; kc < ND; kc += 128) {
    __syncthreads();
    {
      int row = t >> 4, c8 = (t & 15) * 8;
      *(uint4*)&xl[row][c8] = *(const uint4*)(xb + (size_t)(b*NT + kid[row]) * ND + kc + c8);
    }
    __syncthreads();
    #pragma unroll 1
    for (int sub = 0; sub < 8; ++sub) {
      s16x8 k0 = *(const s16x8*)(wkr + kc + sub*16);
      s16x8 k1 = *(const s16x8*)(wkr + kc + sub*16 + 8);
      s16x8 v0 = *(const s16x8*)(wvr + kc + sub*16);
      s16x8 v1 = *(const s16x8*)(wvr + kc + sub*16 + 8);
      float kf[16], vf2[16];
      #pragma unroll
      for (int j = 0; j < 8; ++j) {
        kf[j]  = bf2f((ushort)k0[j]); kf[8+j]  = bf2f((ushort)k1[j]);
        vf2[j] = bf2f((ushort)v0[j]); vf2[8+j] = bf2f((ushort)v1[j]);
      }
      #pragma unroll
      for (int kk = 0; kk < 4; ++kk) {
        #pragma unroll
        for (int j = 0; j < 16; ++j) {
          float xvv = bf2f(xl[kq*4 + kk][sub*16 + j]);
          ak[kk] += xvv * kf[j];
          av[kk] += xvv * vf2[j];
        }
      }
    }
  }
  #pragma unroll
  for (int kk = 0; kk < 4; ++kk) {
    int key = gy*16 + kq*4 + kk;
    ksp[((size_t)bh*NK + key)*NHD + d] = f2bf(ak[kk]);
    vtsp[((size_t)bh*NHD + d)*NK + key] = f2bf(av[kk]);   // transposed for PV B-frags
  }
}

// ---- m97-structure NT GEMM: C[M,N] = A[M,K](bf16) * B[N,K]^T(bf16) ----
template<int STORE_BF16>
__global__ __launch_bounds__(256) void gemm_nt_kernel(
    const ushort* __restrict__ A, const ushort* __restrict__ Bw,
    void* __restrict__ Cout, int M, int N, int K) {
  __shared__ __align__(16) ushort As[2][4096];
  __shared__ __align__(16) ushort Bs[2][4096];
  int nbn = N >> 7;
  int nwg = (M >> 7) * nbn;
  int bid = blockIdx.x;
  int qq = nwg >> 3;                       // nwg % 8 == 0 for our shapes
  int wg = (bid & 7) * qq + (bid >> 3);    // XCD-aware swizzle
  int tm = wg / nbn, tn = wg % nbn;
  int t = threadIdx.x, w = t >> 6, l = t & 63;
  int wm = (w >> 1) * 64, wn = (w & 1) * 64;
  const ushort* Abase = A + (size_t)tm * 128 * K;
  const ushort* Bbase = Bw + (size_t)tn * 128 * K;
  int row0 = t >> 2, c8 = (t & 3) * 8;
  int row1 = (256 + t) >> 2;
  f32x4 acc[4][4];
  #pragma unroll
  for (int i = 0; i < 4; ++i)
    #pragma unroll
    for (int j = 0; j < 4; ++j)
      #pragma unroll
      for (int r = 0; r < 4; ++r) acc[i][j][r] = 0.f;

  #define STAGE(buf, kk) do { \
    __builtin_amdgcn_global_load_lds((gas1_t)(Abase + (size_t)row0*K + (kk) + c8), (las3_t)&As[buf][(w*64)*8], 16, 0, 0); \
    __builtin_amdgcn_global_load_lds((gas1_t)(Abase + (size_t)row1*K + (kk) + c8), (las3_t)&As[buf][(256 + w*64)*8], 16, 0, 0); \
    __builtin_amdgcn_global_load_lds((gas1_t)(Bbase + (size_t)row0*K + (kk) + c8), (las3_t)&Bs[buf][(w*64)*8], 16, 0, 0); \
    __builtin_amdgcn_global_load_lds((gas1_t)(Bbase + (size_t)row1*K + (kk) + c8), (las3_t)&Bs[buf][(256 + w*64)*8], 16, 0, 0); \
  } while (0)

  STAGE(0, 0);
  __syncthreads();
  int nk = K >> 5;
  int aoff = (l & 15) * 32 + (l >> 4) * 8;
  for (int kt = 0; kt < nk; ++kt) {
    int cur = kt & 1;
    if (kt + 1 < nk) STAGE(cur ^ 1, (kt + 1) * 32);
    s16x8 af[4], bfr[4];
    #pragma unroll
    for (int mi = 0; mi < 4; ++mi) af[mi] = *(const s16x8*)&As[cur][(wm + mi*16)*32 + aoff];
    #pragma unroll
    for (int ni = 0; ni < 4; ++ni) bfr[ni] = *(const s16x8*)&Bs[cur][(wn + ni*16)*32 + aoff];
    #pragma unroll
    for (int mi = 0; mi < 4; ++mi)
      #pragma unroll
      for (int ni = 0; ni < 4; ++ni)
        acc[mi][ni] = __builtin_amdgcn_mfma_f32_16x16x32_bf16(af[mi], bfr[ni], acc[mi][ni], 0, 0, 0);
    __syncthreads();
  }
  #undef STAGE
  int grow = tm*128 + wm + (l >> 4) * 4;
  int gcol = tn*128 + wn + (l & 15);
  #pragma unroll
  for (int mi = 0; mi < 4; ++mi)
    #pragma unroll
    for (int ni = 0; ni < 4; ++ni)
      #pragma unroll
      for (int r = 0; r < 4; ++r) {
        size_t off = (size_t)(grow + mi*16 + r) * N + gcol + ni*16;
        if (STORE_BF16) ((ushort*)Cout)[off] = f2bf(acc[mi][ni][r]);
        else            ((float*)Cout)[off]  = acc[mi][ni][r];
      }
}

// ---- attention vs 64 keys: per-wave 64 q-rows; K/V frags live in registers ----
__global__ __launch_bounds__(256) void attn_kernel(
    const ushort* __restrict__ qg, const ushort* __restrict__ ksp,
    const ushort* __restrict__ vtsp, ushort* __restrict__ aout) {
  int bh = blockIdx.y;
  int b = bh >> 4, h = bh & 15;
  int t = threadIdx.x, w = t >> 6, l = t & 63;
  __shared__ __align__(16) ushort Pl[4][1024];   // per-wave 16x64 P tile (XOR-swizzled)
  const ushort* kb = ksp + (size_t)bh * NK * NHD;
  const ushort* vb = vtsp + (size_t)bh * NHD * NK;
  s16x8 kf[2][4], vf[2][4];
  #pragma unroll
  for (int ks = 0; ks < 2; ++ks)
    #pragma unroll
    for (int ni = 0; ni < 4; ++ni) {
      kf[ks][ni] = *(const s16x8*)&kb[(size_t)(ni*16 + (l & 15))*NHD + ks*32 + (l >> 4)*8];
      vf[ks][ni] = *(const s16x8*)&vb[(size_t)(ni*16 + (l & 15))*NK + ks*32 + (l >> 4)*8];
    }
  int rowbase = blockIdx.x * 256 + w * 64;
  #pragma unroll 1
  for (int mi = 0; mi < 4; ++mi) {
    int r0 = rowbase + mi * 16;
    s16x8 af[2];
    #pragma unroll
    for (int ks = 0; ks < 2; ++ks)
      af[ks] = *(const s16x8*)&qg[(size_t)(b*NT + r0 + (l & 15))*ND + h*NHD + ks*32 + (l >> 4)*8];
    f32x4 sc[4];
    #pragma unroll
    for (int ni = 0; ni < 4; ++ni) {
      f32x4 z; z[0]=0.f; z[1]=0.f; z[2]=0.f; z[3]=0.f;
      z = __builtin_amdgcn_mfma_f32_16x16x32_bf16(af[0], kf[0][ni], z, 0, 0, 0);
      sc[ni] = __builtin_amdgcn_mfma_f32_16x16x32_bf16(af[1], kf[1][ni], z, 0, 0, 0);
    }
    #pragma unroll
    for (int r = 0; r < 4; ++r) {
      float v0 = sc[0][r]*0.125f, v1 = sc[1][r]*0.125f;
      float v2 = sc[2][r]*0.125f, v3 = sc[3][r]*0.125f;
      float m = fmaxf(fmaxf(v0, v1), fmaxf(v2, v3));
      #pragma unroll
      for (int mm = 8; mm >= 1; mm >>= 1) m = fmaxf(m, __shfl_xor(m, mm, 64));
      float e0 = __expf(v0 - m), e1 = __expf(v1 - m);
      float e2 = __expf(v2 - m), e3 = __expf(v3 - m);
      float s = e0 + e1 + e2 + e3;
      #pragma unroll
      for (int mm = 8; mm >= 1; mm >>= 1) s += __shfl_xor(s, mm, 64);
      float inv = 1.f / s;
      int prow = (l >> 4)*4 + r;
      int lo = l & 7, hb = (l >> 3) & 1, sw = prow & 7;
      Pl[w][prow*64 + ((0 + hb) ^ sw)*8 + lo] = f2bf(e0 * inv);
      Pl[w][prow*64 + ((2 + hb) ^ sw)*8 + lo] = f2bf(e1 * inv);
      Pl[w][prow*64 + ((4 + hb) ^ sw)*8 + lo] = f2bf(e2 * inv);
      Pl[w][prow*64 + ((6 + hb) ^ sw)*8 + lo] = f2bf(e3 * inv);
    }
    s16x8 pf[2];
    #pragma unroll
    for (int ks = 0; ks < 2; ++ks)
      pf[ks] = *(const s16x8*)&Pl[w][(l & 15)*64 + ((ks*4 + (l >> 4)) ^ (l & 7))*8];
    f32x4 oc[4];
    #pragma unroll
    for (int ni = 0; ni < 4; ++ni) {
      f32x4 z; z[0]=0.f; z[1]=0.f; z[2]=0.f; z[3]=0.f;
      z = __builtin_amdgcn_mfma_f32_16x16x32_bf16(pf[0], vf[0][ni], z, 0, 0, 0);
      oc[ni] = __builtin_amdgcn_mfma_f32_16x16x32_bf16(pf[1], vf[1][ni], z, 0, 0, 0);
    }
    #pragma unroll
    for (int ni = 0; ni < 4; ++ni)
      #pragma unroll
      for (int r = 0; r < 4; ++r) {
        int row = r0 + (l >> 4)*4 + r;
        aout[(size_t)(b*NT + row)*ND + h*NHD + ni*16 + (l & 15)] = f2bf(oc[ni][r]);
      }
  }
}

extern "C" void kernel_launch(void* const* d_in, const int* in_sizes, int n_in,
                              void* d_out, int out_size, void* d_ws, size_t ws_size,
                              hipStream_t stream) {
  (void)in_sizes; (void)n_in; (void)out_size; (void)ws_size;
  const float* x  = (const float*)d_in[0];
  const float* Wq = (const float*)d_in[1];
  const float* Wk = (const float*)d_in[2];
  const float* Wv = (const float*)d_in[3];
  const float* Wo = (const float*)d_in[4];
  const float* wscore = (const float*)d_in[5];

  char* base = (char*)d_ws;
  ushort* xb     = (ushort*)(base + 0);           // 64 MiB  (reused as attn out)
  ushort* qb     = (ushort*)(base + 67108864);    // 64 MiB
  float*  scores = (float*) (base + 134217728);   // 2 MiB
  float*  u      = (float*) (base + 136314880);   // 64 KiB
  ushort* wqb    = (ushort*)(base + 136380416);   // 2 MiB
  ushort* wkb    = (ushort*)(base + 138477568);   // 2 MiB
  ushort* wvb    = (ushort*)(base + 140574720);   // 2 MiB
  ushort* wob    = (ushort*)(base + 142671872);   // 2 MiB
  int*    tidx   = (int*)   (base + 144769024);   // 16 KiB
  ushort* ksp    = (ushort*)(base + 144785408);   // 512 KiB
  ushort* vtsp   = (ushort*)(base + 145309696);   // 512 KiB
  ushort* aout   = xb;   // xb is dead after gemm_q + sparse_kv

  convert_w_kernel<<<dim3(4096), dim3(256), 0, stream>>>(Wq, Wk, Wv, Wo, wqb, wkb, wvb, wob);
  prep_u_kernel<<<dim3(64), dim3(256), 0, stream>>>(Wk, wscore, u);
  prep_x_kernel<<<dim3(512), dim3(256), 0, stream>>>(x, u, xb, scores);
  topk_kernel<<<dim3(64), dim3(256), 0, stream>>>(scores, tidx);
  sparse_kv_kernel<<<dim3(64, 4), dim3(256), 0, stream>>>(xb, wkb, wvb, tidx, ksp, vtsp);
  gemm_nt_kernel<1><<<dim3(2048), dim3(256), 0, stream>>>(xb, wqb, (void*)qb, NM, ND, ND);
  attn_kernel<<<dim3(32, 64), dim3(256), 0, stream>>>(qb, ksp, vtsp, aout);
  gemm_nt_kernel<0><<<dim3(2048), dim3(256), 0, stream>>>(aout, wob, d_out, NM, ND, ND);
}

// Round 2
// 387.863 us; speedup vs baseline: 1.3167x; 1.3167x over previous
//
#include <hip/hip_runtime.h>
#include <hip/hip_bf16.h>
#include <stdint.h>

#define NB 4
#define NT 8192
#define ND 1024
#define NH 16
#define NHD 64
#define NK 64        // top-k
#define NM (NB*NT)   // 32768

typedef __attribute__((ext_vector_type(4))) float f32x4;
typedef __attribute__((ext_vector_type(8))) short s16x8;
typedef const void __attribute__((address_space(1)))* gas1_t;
typedef void __attribute__((address_space(3)))* las3_t;

__device__ __forceinline__ float bf2f(ushort u) {
  union { uint32_t i; float f; } v; v.i = ((uint32_t)u) << 16; return v.f;
}
__device__ __forceinline__ ushort f2bf(float f) {
  union { float f; uint32_t i; } v; v.f = f;
  uint32_t r = v.i + 0x7FFFu + ((v.i >> 16) & 1u);
  return (ushort)(r >> 16);
}
__device__ __forceinline__ uint32_t f2ord(uint32_t u) {
  return (u & 0x80000000u) ? ~u : (u | 0x80000000u);
}

// ---- convert the four weight matrices to bf16 ----
__global__ __launch_bounds__(256) void convert_w_kernel(
    const float* __restrict__ Wq, const float* __restrict__ Wk,
    const float* __restrict__ Wv, const float* __restrict__ Wo,
    ushort* __restrict__ wqb, ushort* __restrict__ wkb,
    ushort* __restrict__ wvb, ushort* __restrict__ wob) {
  int i = blockIdx.x * 256 + threadIdx.x;   // grid covers exactly 1M
  wqb[i] = f2bf(Wq[i]); wkb[i] = f2bf(Wk[i]);
  wvb[i] = f2bf(Wv[i]); wob[i] = f2bf(Wo[i]);
}

// ---- u[h][e] = sum_d wscore[d] * Wk[h*64+d][e]  (fp32, exact path for topk) ----
__global__ __launch_bounds__(256) void prep_u_kernel(
    const float* __restrict__ Wk, const float* __restrict__ wscore,
    float* __restrict__ u) {
  int e = (blockIdx.x & 3) * 256 + threadIdx.x;
  int h = blockIdx.x >> 2;
  float acc = 0.f;
  #pragma unroll 8
  for (int d = 0; d < NHD; ++d) acc += wscore[d] * Wk[(size_t)(h*NHD + d)*ND + e];
  u[h*ND + e] = acc;
}

// ---- x -> bf16, and fp32 indexer scores[b*16+h][t] = x_row . u[h] ----
__global__ __launch_bounds__(256) void prep_x_kernel(
    const float* __restrict__ x, const float* __restrict__ u,
    ushort* __restrict__ xb, float* __restrict__ scores) {
  __shared__ float ul[NH*ND];   // 64 KiB
  int t = threadIdx.x;
  {
    const float4* u4 = (const float4*)u;
    float4* l4 = (float4*)ul;
    for (int i = t; i < NH*ND/4; i += 256) l4[i] = u4[i];
  }
  __syncthreads();
  int w = t >> 6, l = t & 63;
  #pragma unroll 1
  for (int rr = 0; rr < 16; ++rr) {
    int row = blockIdx.x * 64 + w * 16 + rr;   // global token row (b*T+t)
    const float4* xr = (const float4*)(x + (size_t)row * ND);
    float4 xv[4];
    #pragma unroll
    for (int j = 0; j < 4; ++j) xv[j] = xr[l + j*64];     // elems l*4 + j*256
    #pragma unroll
    for (int j = 0; j < 4; ++j) {
      ushort4 o;
      o.x = f2bf(xv[j].x); o.y = f2bf(xv[j].y); o.z = f2bf(xv[j].z); o.w = f2bf(xv[j].w);
      *(ushort4*)(xb + (size_t)row * ND + l*4 + j*256) = o;
    }
    int boff = ((row >> 13) << 4);
    int tt = row & (NT - 1);
    #pragma unroll 1
    for (int h = 0; h < NH; ++h) {
      const float4* ur = (const float4*)(ul + h*ND);
      float p = 0.f;
      #pragma unroll
      for (int j = 0; j < 4; ++j) {
        float4 uv = ur[l + j*64];
        p += xv[j].x*uv.x + xv[j].y*uv.y + xv[j].z*uv.z + xv[j].w*uv.w;
      }
      #pragma unroll
      for (int m = 32; m >= 1; m >>= 1) p += __shfl_xor(p, m, 64);
      if (l == 0) scores[(size_t)(boff + h) * NT + tt] = p;
    }
  }
}

// ---- top-64 per (b,h) via single-pass radix-select (12-bit histogram) ----
// Only the SET matters downstream (softmax over the selected keys is
// permutation-invariant); ties at the boundary bin break by lower index,
// matching jax.lax.top_k's equal-value order.
__global__ __launch_bounds__(256) void topk_kernel(
    const float* __restrict__ scores, int* __restrict__ tidx) {
  int bh = blockIdx.x, t = threadIdx.x;
  __shared__ uint32_t keys[NT];      // 32 KiB order-preserving keys
  __shared__ int hist[4096];         // 16 KiB
  __shared__ uint32_t ck[512];
  __shared__ int ci[512];
  __shared__ int chunksum[256];
  __shared__ int s_binB, s_c0;
  __shared__ int cnt_hi, cnt_cand;

  for (int i = t; i < 4096; i += 256) hist[i] = 0;
  if (t == 0) { cnt_hi = 0; cnt_cand = 0; }
  __syncthreads();
  const uint4* sg = (const uint4*)(scores + (size_t)bh * NT);
  for (int i = t; i < NT/4; i += 256) {
    uint4 v = sg[i];
    uint32_t k0 = f2ord(v.x), k1 = f2ord(v.y), k2 = f2ord(v.z), k3 = f2ord(v.w);
    keys[i*4+0] = k0; keys[i*4+1] = k1; keys[i*4+2] = k2; keys[i*4+3] = k3;
    atomicAdd(&hist[k0 >> 20], 1); atomicAdd(&hist[k1 >> 20], 1);
    atomicAdd(&hist[k2 >> 20], 1); atomicAdd(&hist[k3 >> 20], 1);
  }
  __syncthreads();
  {  // per-thread 16-bin chunk sums, ordered from the TOP of the key space
    int hi = 4095 - t * 16;
    int s = 0;
    #pragma unroll
    for (int j = 0; j < 16; ++j) s += hist[hi - j];
    chunksum[t] = s;
  }
  __syncthreads();
  if (t == 0) {   // find boundary bin B: count(bins>B) < NK <= count(bins>=B)
    int cum = 0, c = 0;
    while (cum + chunksum[c] < NK) { cum += chunksum[c]; ++c; }
    int bin = 4095 - c * 16;
    while (cum + hist[bin] < NK) { cum += hist[bin]; --bin; }
    s_binB = bin; s_c0 = cum;
  }
  __syncthreads();
  int binB = s_binB, c0 = s_c0;
  for (int i = t; i < NT; i += 256) {
    int b = keys[i] >> 20;
    if (b > binB) {
      int p = atomicAdd(&cnt_hi, 1);
      tidx[bh*NK + p] = i;                    // definitely in top-64
    } else if (b == binB) {
      int p = atomicAdd(&cnt_cand, 1);
      if (p < 512) { ck[p] = keys[i]; ci[p] = i; }
    }
  }
  __syncthreads();
  int nc = cnt_cand; if (nc > 512) nc = 512;
  int need = NK - c0;
  // counting-rank inside the boundary bin (parallel, barrier-free)
  for (int p = t; p < nc; p += 256) {
    uint32_t myk = ck[p]; int myi = ci[p];
    int rank = 0;
    for (int j = 0; j < nc; ++j) {
      uint32_t kj = ck[j];
      rank += (kj > myk || (kj == myk && ci[j] < myi)) ? 1 : 0;
    }
    if (rank < need) tidx[bh*NK + c0 + rank] = myi;
  }
}

// ---- project ONLY the 64 selected rows per (b,h) into K_sp[key][d], V^T_sp[d][key] ----
__global__ __launch_bounds__(256) void sparse_kv_kernel(
    const ushort* __restrict__ xb, const ushort* __restrict__ wkb,
    const ushort* __restrict__ wvb, const int* __restrict__ tidx,
    ushort* __restrict__ ksp, ushort* __restrict__ vtsp) {
  int bh = blockIdx.x, gy = blockIdx.y;
  int b = bh >> 4, h = bh & 15;
  int t = threadIdx.x;
  __shared__ __align__(16) ushort xl[16][128];
  __shared__ int kid[16];
  if (t < 16) kid[t] = tidx[bh*NK + gy*16 + t];
  int d = t & 63, kq = t >> 6;      // wave = one kq -> LDS reads broadcast
  float ak[4] = {0.f,0.f,0.f,0.f}, av[4] = {0.f,0.f,0.f,0.f};
  const ushort* wkr = wkb + (size_t)(h*NHD + d) * ND;
  const ushort* wvr = wvb + (size_t)(h*NHD + d) * ND;
  for (int kc = 0; kc < ND; kc += 128) {
    __syncthreads();
    {
      int row = t >> 4, c8 = (t & 15) * 8;
      *(uint4*)&xl[row][c8] = *(const uint4*)(xb + (size_t)(b*NT + kid[row]) * ND + kc + c8);
    }
    __syncthreads();
    #pragma unroll 1
    for (int sub = 0; sub < 8; ++sub) {
      s16x8 k0 = *(const s16x8*)(wkr + kc + sub*16);
      s16x8 k1 = *(const s16x8*)(wkr + kc + sub*16 + 8);
      s16x8 v0 = *(const s16x8*)(wvr + kc + sub*16);
      s16x8 v1 = *(const s16x8*)(wvr + kc + sub*16 + 8);
      float kf[16], vf2[16];
      #pragma unroll
      for (int j = 0; j < 8; ++j) {
        kf[j]  = bf2f((ushort)k0[j]); kf[8+j]  = bf2f((ushort)k1[j]);
        vf2[j] = bf2f((ushort)v0[j]); vf2[8+j] = bf2f((ushort)v1[j]);
      }
      #pragma unroll
      for (int kk = 0; kk < 4; ++kk) {
        #pragma unroll
        for (int j = 0; j < 16; ++j) {
          float xvv = bf2f(xl[kq*4 + kk][sub*16 + j]);
          ak[kk] += xvv * kf[j];
          av[kk] += xvv * vf2[j];
        }
      }
    }
  }
  #pragma unroll
  for (int kk = 0; kk < 4; ++kk) {
    int key = gy*16 + kq*4 + kk;
    ksp[((size_t)bh*NK + key)*NHD + d] = f2bf(ak[kk]);
    vtsp[((size_t)bh*NHD + d)*NK + key] = f2bf(av[kk]);   // transposed for PV B-frags
  }
}

// ---- m97-structure NT GEMM: C[M,N] = A[M,K](bf16) * B[N,K]^T(bf16) ----
template<int STORE_BF16>
__global__ __launch_bounds__(256) void gemm_nt_kernel(
    const ushort* __restrict__ A, const ushort* __restrict__ Bw,
    void* __restrict__ Cout, int M, int N, int K) {
  __shared__ __align__(16) ushort As[2][4096];
  __shared__ __align__(16) ushort Bs[2][4096];
  int nbn = N >> 7;
  int nwg = (M >> 7) * nbn;
  int bid = blockIdx.x;
  int qq = nwg >> 3;                       // nwg % 8 == 0 for our shapes
  int wg = (bid & 7) * qq + (bid >> 3);    // XCD-aware swizzle
  int tm = wg / nbn, tn = wg % nbn;
  int t = threadIdx.x, w = t >> 6, l = t & 63;
  int wm = (w >> 1) * 64, wn = (w & 1) * 64;
  const ushort* Abase = A + (size_t)tm * 128 * K;
  const ushort* Bbase = Bw + (size_t)tn * 128 * K;
  int row0 = t >> 2, c8 = (t & 3) * 8;
  int row1 = (256 + t) >> 2;
  f32x4 acc[4][4];
  #pragma unroll
  for (int i = 0; i < 4; ++i)
    #pragma unroll
    for (int j = 0; j < 4; ++j)
      #pragma unroll
      for (int r = 0; r < 4; ++r) acc[i][j][r] = 0.f;

  #define STAGE(buf, kk) do { \
    __builtin_amdgcn_global_load_lds((gas1_t)(Abase + (size_t)row0*K + (kk) + c8), (las3_t)&As[buf][(w*64)*8], 16, 0, 0); \
    __builtin_amdgcn_global_load_lds((gas1_t)(Abase + (size_t)row1*K + (kk) + c8), (las3_t)&As[buf][(256 + w*64)*8], 16, 0, 0); \
    __builtin_amdgcn_global_load_lds((gas1_t)(Bbase + (size_t)row0*K + (kk) + c8), (las3_t)&Bs[buf][(w*64)*8], 16, 0, 0); \
    __builtin_amdgcn_global_load_lds((gas1_t)(Bbase + (size_t)row1*K + (kk) + c8), (las3_t)&Bs[buf][(256 + w*64)*8], 16, 0, 0); \
  } while (0)

  STAGE(0, 0);
  __syncthreads();
  int nk = K >> 5;
  int aoff = (l & 15) * 32 + (l >> 4) * 8;
  for (int kt = 0; kt < nk; ++kt) {
    int cur = kt & 1;
    if (kt + 1 < nk) STAGE(cur ^ 1, (kt + 1) * 32);
    s16x8 af[4], bfr[4];
    #pragma unroll
    for (int mi = 0; mi < 4; ++mi) af[mi] = *(const s16x8*)&As[cur][(wm + mi*16)*32 + aoff];
    #pragma unroll
    for (int ni = 0; ni < 4; ++ni) bfr[ni] = *(const s16x8*)&Bs[cur][(wn + ni*16)*32 + aoff];
    #pragma unroll
    for (int mi = 0; mi < 4; ++mi)
      #pragma unroll
      for (int ni = 0; ni < 4; ++ni)
        acc[mi][ni] = __builtin_amdgcn_mfma_f32_16x16x32_bf16(af[mi], bfr[ni], acc[mi][ni], 0, 0, 0);
    __syncthreads();
  }
  #undef STAGE
  int grow = tm*128 + wm + (l >> 4) * 4;
  int gcol = tn*128 + wn + (l & 15);
  #pragma unroll
  for (int mi = 0; mi < 4; ++mi)
    #pragma unroll
    for (int ni = 0; ni < 4; ++ni)
      #pragma unroll
      for (int r = 0; r < 4; ++r) {
        size_t off = (size_t)(grow + mi*16 + r) * N + gcol + ni*16;
        if (STORE_BF16) ((ushort*)Cout)[off] = f2bf(acc[mi][ni][r]);
        else            ((float*)Cout)[off]  = acc[mi][ni][r];
      }
}

// ---- attention vs 64 keys: per-wave 64 q-rows; K/V frags live in registers ----
__global__ __launch_bounds__(256) void attn_kernel(
    const ushort* __restrict__ qg, const ushort* __restrict__ ksp,
    const ushort* __restrict__ vtsp, ushort* __restrict__ aout) {
  int bh = blockIdx.y;
  int b = bh >> 4, h = bh & 15;
  int t = threadIdx.x, w = t >> 6, l = t & 63;
  __shared__ __align__(16) ushort Pl[4][1024];   // per-wave 16x64 P tile (XOR-swizzled)
  const ushort* kb = ksp + (size_t)bh * NK * NHD;
  const ushort* vb = vtsp + (size_t)bh * NHD * NK;
  s16x8 kf[2][4], vf[2][4];
  #pragma unroll
  for (int ks = 0; ks < 2; ++ks)
    #pragma unroll
    for (int ni = 0; ni < 4; ++ni) {
      kf[ks][ni] = *(const s16x8*)&kb[(size_t)(ni*16 + (l & 15))*NHD + ks*32 + (l >> 4)*8];
      vf[ks][ni] = *(const s16x8*)&vb[(size_t)(ni*16 + (l & 15))*NK + ks*32 + (l >> 4)*8];
    }
  int rowbase = blockIdx.x * 256 + w * 64;
  #pragma unroll 1
  for (int mi = 0; mi < 4; ++mi) {
    int r0 = rowbase + mi * 16;
    s16x8 af[2];
    #pragma unroll
    for (int ks = 0; ks < 2; ++ks)
      af[ks] = *(const s16x8*)&qg[(size_t)(b*NT + r0 + (l & 15))*ND + h*NHD + ks*32 + (l >> 4)*8];
    f32x4 sc[4];
    #pragma unroll
    for (int ni = 0; ni < 4; ++ni) {
      f32x4 z; z[0]=0.f; z[1]=0.f; z[2]=0.f; z[3]=0.f;
      z = __builtin_amdgcn_mfma_f32_16x16x32_bf16(af[0], kf[0][ni], z, 0, 0, 0);
      sc[ni] = __builtin_amdgcn_mfma_f32_16x16x32_bf16(af[1], kf[1][ni], z, 0, 0, 0);
    }
    #pragma unroll
    for (int r = 0; r < 4; ++r) {
      float v0 = sc[0][r]*0.125f, v1 = sc[1][r]*0.125f;
      float v2 = sc[2][r]*0.125f, v3 = sc[3][r]*0.125f;
      float m = fmaxf(fmaxf(v0, v1), fmaxf(v2, v3));
      #pragma unroll
      for (int mm = 8; mm >= 1; mm >>= 1) m = fmaxf(m, __shfl_xor(m, mm, 64));
      float e0 = __expf(v0 - m), e1 = __expf(v1 - m);
      float e2 = __expf(v2 - m), e3 = __expf(v3 - m);
      float s = e0 + e1 + e2 + e3;
      #pragma unroll
      for (int mm = 8; mm >= 1; mm >>= 1) s += __shfl_xor(s, mm, 64);
      float inv = 1.f / s;
      int prow = (l >> 4)*4 + r;
      int lo = l & 7, hb = (l >> 3) & 1, sw = prow & 7;
      Pl[w][prow*64 + ((0 + hb) ^ sw)*8 + lo] = f2bf(e0 * inv);
      Pl[w][prow*64 + ((2 + hb) ^ sw)*8 + lo] = f2bf(e1 * inv);
      Pl[w][prow*64 + ((4 + hb) ^ sw)*8 + lo] = f2bf(e2 * inv);
      Pl[w][prow*64 + ((6 + hb) ^ sw)*8 + lo] = f2bf(e3 * inv);
    }
    s16x8 pf[2];
    #pragma unroll
    for (int ks = 0; ks < 2; ++ks)
      pf[ks] = *(const s16x8*)&Pl[w][(l & 15)*64 + ((ks*4 + (l >> 4)) ^ (l & 7))*8];
    f32x4 oc[4];
    #pragma unroll
    for (int ni = 0; ni < 4; ++ni) {
      f32x4 z; z[0]=0.f; z[1]=0.f; z[2]=0.f; z[3]=0.f;
      z = __builtin_amdgcn_mfma_f32_16x16x32_bf16(pf[0], vf[0][ni], z, 0, 0, 0);
      oc[ni] = __builtin_amdgcn_mfma_f32_16x16x32_bf16(pf[1], vf[1][ni], z, 0, 0, 0);
    }
    #pragma unroll
    for (int ni = 0; ni < 4; ++ni)
      #pragma unroll
      for (int r = 0; r < 4; ++r) {
        int row = r0 + (l >> 4)*4 + r;
        aout[(size_t)(b*NT + row)*ND + h*NHD + ni*16 + (l & 15)] = f2bf(oc[ni][r]);
      }
  }
}

extern "C" void kernel_launch(void* const* d_in, const int* in_sizes, int n_in,
                              void* d_out, int out_size, void* d_ws, size_t ws_size,
                              hipStream_t stream) {
  (void)in_sizes; (void)n_in; (void)out_size; (void)ws_size;
  const float* x  = (const float*)d_in[0];
  const float* Wq = (const float*)d_in[1];
  const float* Wk = (const float*)d_in[2];
  const float* Wv = (const float*)d_in[3];
  const float* Wo = (const float*)d_in[4];
  const float* wscore = (const float*)d_in[5];

  char* base = (char*)d_ws;
  ushort* xb     = (ushort*)(base + 0);           // 64 MiB  (reused as attn out)
  ushort* qb     = (ushort*)(base + 67108864);    // 64 MiB
  float*  scores = (float*) (base + 134217728);   // 2 MiB
  float*  u      = (float*) (base + 136314880);   // 64 KiB
  ushort* wqb    = (ushort*)(base + 136380416);   // 2 MiB
  ushort* wkb    = (ushort*)(base + 138477568);   // 2 MiB
  ushort* wvb    = (ushort*)(base + 140574720);   // 2 MiB
  ushort* wob    = (ushort*)(base + 142671872);   // 2 MiB
  int*    tidx   = (int*)   (base + 144769024);   // 16 KiB
  ushort* ksp    = (ushort*)(base + 144785408);   // 512 KiB
  ushort* vtsp   = (ushort*)(base + 145309696);   // 512 KiB
  ushort* aout   = xb;   // xb is dead after gemm_q + sparse_kv

  convert_w_kernel<<<dim3(4096), dim3(256), 0, stream>>>(Wq, Wk, Wv, Wo, wqb, wkb, wvb, wob);
  prep_u_kernel<<<dim3(64), dim3(256), 0, stream>>>(Wk, wscore, u);
  prep_x_kernel<<<dim3(512), dim3(256), 0, stream>>>(x, u, xb, scores);
  topk_kernel<<<dim3(64), dim3(256), 0, stream>>>(scores, tidx);
  sparse_kv_kernel<<<dim3(64, 4), dim3(256), 0, stream>>>(xb, wkb, wvb, tidx, ksp, vtsp);
  gemm_nt_kernel<1><<<dim3(2048), dim3(256), 0, stream>>>(xb, wqb, (void*)qb, NM, ND, ND);
  attn_kernel<<<dim3(32, 64), dim3(256), 0, stream>>>(qb, ksp, vtsp, aout);
  gemm_nt_kernel<0><<<dim3(2048), dim3(256), 0, stream>>>(aout, wob, d_out, NM, ND, ND);
}

// Round 3
// 338.158 us; speedup vs baseline: 1.5102x; 1.1470x over previous
//
#include <hip/hip_runtime.h>
#include <hip/hip_bf16.h>
#include <stdint.h>

#define NB 4
#define NT 8192
#define ND 1024
#define NH 16
#define NHD 64
#define NK 64        // top-k
#define NM (NB*NT)   // 32768

typedef __attribute__((ext_vector_type(4))) float f32x4;
typedef __attribute__((ext_vector_type(8))) short s16x8;
typedef const void __attribute__((address_space(1)))* gas1_t;
typedef void __attribute__((address_space(3)))* las3_t;

__device__ __forceinline__ float bf2f(ushort u) {
  union { uint32_t i; float f; } v; v.i = ((uint32_t)u) << 16; return v.f;
}
__device__ __forceinline__ ushort f2bf(float f) {
  union { float f; uint32_t i; } v; v.f = f;
  uint32_t r = v.i + 0x7FFFu + ((v.i >> 16) & 1u);
  return (ushort)(r >> 16);
}
__device__ __forceinline__ uint32_t f2ord(uint32_t u) {
  return (u & 0x80000000u) ? ~u : (u | 0x80000000u);
}

// ---- convert the four weight matrices to bf16 ----
__global__ __launch_bounds__(256) void convert_w_kernel(
    const float* __restrict__ Wq, const float* __restrict__ Wk,
    const float* __restrict__ Wv, const float* __restrict__ Wo,
    ushort* __restrict__ wqb, ushort* __restrict__ wkb,
    ushort* __restrict__ wvb, ushort* __restrict__ wob) {
  int i = blockIdx.x * 256 + threadIdx.x;   // grid covers exactly 1M
  wqb[i] = f2bf(Wq[i]); wkb[i] = f2bf(Wk[i]);
  wvb[i] = f2bf(Wv[i]); wob[i] = f2bf(Wo[i]);
}

// ---- u[h][e] = sum_d wscore[d] * Wk[h*64+d][e]  (fp32, exact path for topk) ----
__global__ __launch_bounds__(256) void prep_u_kernel(
    const float* __restrict__ Wk, const float* __restrict__ wscore,
    float* __restrict__ u) {
  int e = (blockIdx.x & 3) * 256 + threadIdx.x;
  int h = blockIdx.x >> 2;
  float acc = 0.f;
  #pragma unroll 8
  for (int d = 0; d < NHD; ++d) acc += wscore[d] * Wk[(size_t)(h*NHD + d)*ND + e];
  u[h*ND + e] = acc;
}

// ---- x -> bf16, and fp32 indexer scores[b*16+h][t] = x_row . u[h] ----
// u lives in VGPRs (lane owns u[0..15][its 4 elems]); packed butterfly reduce.
__global__ __launch_bounds__(256) void prep_x_kernel(
    const float* __restrict__ x, const float* __restrict__ u,
    ushort* __restrict__ xb, float* __restrict__ scores) {
  __shared__ float pbuf[16][4][17];   // [row-in-batch][wave][h], padded
  int t = threadIdx.x, w = t >> 6, l = t & 63;
  int e0 = w * 256 + l * 4;           // this lane's 4-elem slice of the row
  float4 uv[16];
  #pragma unroll
  for (int h = 0; h < 16; ++h) uv[h] = *(const float4*)(u + h * ND + e0);
  int row0 = blockIdx.x * 32;
  int boff = ((row0 >> 13) << 4);      // b*16
  int tt0 = row0 & (NT - 1);
  for (int batch = 0; batch < 2; ++batch) {   // 2 batches of 16 rows
    #pragma unroll 2
    for (int rr = 0; rr < 16; ++rr) {
      int row = row0 + batch * 16 + rr;
      float4 xv = *(const float4*)(x + (size_t)row * ND + e0);
      ushort4 o; o.x = f2bf(xv.x); o.y = f2bf(xv.y); o.z = f2bf(xv.z); o.w = f2bf(xv.w);
      *(ushort4*)(xb + (size_t)row * ND + e0) = o;
      float p[16];
      #pragma unroll
      for (int h = 0; h < 16; ++h)
        p[h] = xv.x*uv[h].x + xv.y*uv[h].y + xv.z*uv[h].z + xv.w*uv[h].w;
      // packed butterfly: at stride m keep the h-half matching own lane bit
      float q8[8];
      #pragma unroll
      for (int j = 0; j < 8; ++j) {
        bool hi = (l & 1);
        float keep = hi ? p[2*j+1] : p[2*j];
        float send = hi ? p[2*j]   : p[2*j+1];
        q8[j] = keep + __shfl_xor(send, 1, 64);
      }
      float q4[4];
      #pragma unroll
      for (int j = 0; j < 4; ++j) {
        bool hi = ((l >> 1) & 1);
        float keep = hi ? q8[2*j+1] : q8[2*j];
        float send = hi ? q8[2*j]   : q8[2*j+1];
        q4[j] = keep + __shfl_xor(send, 2, 64);
      }
      float q2[2];
      #pragma unroll
      for (int j = 0; j < 2; ++j) {
        bool hi = ((l >> 2) & 1);
        float keep = hi ? q4[2*j+1] : q4[2*j];
        float send = hi ? q4[2*j]   : q4[2*j+1];
        q2[j] = keep + __shfl_xor(send, 4, 64);
      }
      float q1;
      {
        bool hi = ((l >> 3) & 1);
        float keep = hi ? q2[1] : q2[0];
        float send = hi ? q2[0] : q2[1];
        q1 = keep + __shfl_xor(send, 8, 64);
      }
      q1 += __shfl_xor(q1, 16, 64);
      q1 += __shfl_xor(q1, 32, 64);
      if (l < 16) pbuf[rr][w][l] = q1;   // h = l&15
    }
    __syncthreads();
    {
      int r16 = t & 15, h = t >> 4;      // consecutive t -> consecutive tt (coalesced)
      float s = pbuf[r16][0][h] + pbuf[r16][1][h] + pbuf[r16][2][h] + pbuf[r16][3][h];
      scores[(size_t)(boff + h) * NT + tt0 + batch * 16 + r16] = s;
    }
    __syncthreads();
  }
}

// ---- top-64 per (b,h) via single-pass radix-select (12-bit histogram) ----
// Only the SET matters downstream (softmax over the selected keys is
// permutation-invariant); ties at the boundary bin break by lower index,
// matching jax.lax.top_k's equal-value order.
__global__ __launch_bounds__(256) void topk_kernel(
    const float* __restrict__ scores, int* __restrict__ tidx) {
  int bh = blockIdx.x, t = threadIdx.x;
  __shared__ uint32_t keys[NT];      // 32 KiB order-preserving keys
  __shared__ int hist[4096];         // 16 KiB
  __shared__ uint32_t ck[512];
  __shared__ int ci[512];
  __shared__ int chunksum[256];
  __shared__ int s_binB, s_c0;
  __shared__ int cnt_hi, cnt_cand;

  for (int i = t; i < 4096; i += 256) hist[i] = 0;
  if (t == 0) { cnt_hi = 0; cnt_cand = 0; }
  __syncthreads();
  const uint4* sg = (const uint4*)(scores + (size_t)bh * NT);
  for (int i = t; i < NT/4; i += 256) {
    uint4 v = sg[i];
    uint32_t k0 = f2ord(v.x), k1 = f2ord(v.y), k2 = f2ord(v.z), k3 = f2ord(v.w);
    keys[i*4+0] = k0; keys[i*4+1] = k1; keys[i*4+2] = k2; keys[i*4+3] = k3;
    atomicAdd(&hist[k0 >> 20], 1); atomicAdd(&hist[k1 >> 20], 1);
    atomicAdd(&hist[k2 >> 20], 1); atomicAdd(&hist[k3 >> 20], 1);
  }
  __syncthreads();
  {  // per-thread 16-bin chunk sums, ordered from the TOP of the key space
    int hi = 4095 - t * 16;
    int s = 0;
    #pragma unroll
    for (int j = 0; j < 16; ++j) s += hist[hi - j];
    chunksum[t] = s;
  }
  __syncthreads();
  if (t == 0) {   // find boundary bin B: count(bins>B) < NK <= count(bins>=B)
    int cum = 0, c = 0;
    while (cum + chunksum[c] < NK) { cum += chunksum[c]; ++c; }
    int bin = 4095 - c * 16;
    while (cum + hist[bin] < NK) { cum += hist[bin]; --bin; }
    s_binB = bin; s_c0 = cum;
  }
  __syncthreads();
  int binB = s_binB, c0 = s_c0;
  for (int i = t; i < NT; i += 256) {
    int b = keys[i] >> 20;
    if (b > binB) {
      int p = atomicAdd(&cnt_hi, 1);
      tidx[bh*NK + p] = i;                    // definitely in top-64
    } else if (b == binB) {
      int p = atomicAdd(&cnt_cand, 1);
      if (p < 512) { ck[p] = keys[i]; ci[p] = i; }
    }
  }
  __syncthreads();
  int nc = cnt_cand; if (nc > 512) nc = 512;
  int need = NK - c0;
  // counting-rank inside the boundary bin (parallel, barrier-free)
  for (int p = t; p < nc; p += 256) {
    uint32_t myk = ck[p]; int myi = ci[p];
    int rank = 0;
    for (int j = 0; j < nc; ++j) {
      uint32_t kj = ck[j];
      rank += (kj > myk || (kj == myk && ci[j] < myi)) ? 1 : 0;
    }
    if (rank < need) tidx[bh*NK + c0 + rank] = myi;
  }
}

// ---- project ONLY the 64 selected rows per (b,h) into K_sp[key][d], V^T_sp[d][key] ----
__global__ __launch_bounds__(256) void sparse_kv_kernel(
    const ushort* __restrict__ xb, const ushort* __restrict__ wkb,
    const ushort* __restrict__ wvb, const int* __restrict__ tidx,
    ushort* __restrict__ ksp, ushort* __restrict__ vtsp) {
  int bh = blockIdx.x, gy = blockIdx.y;
  int b = bh >> 4, h = bh & 15;
  int t = threadIdx.x;
  __shared__ __align__(16) ushort xl[16][128];
  __shared__ int kid[16];
  if (t < 16) kid[t] = tidx[bh*NK + gy*16 + t];
  int d = t & 63, kq = t >> 6;      // wave = one kq -> LDS reads broadcast
  float ak[4] = {0.f,0.f,0.f,0.f}, av[4] = {0.f,0.f,0.f,0.f};
  const ushort* wkr = wkb + (size_t)(h*NHD + d) * ND;
  const ushort* wvr = wvb + (size_t)(h*NHD + d) * ND;
  for (int kc = 0; kc < ND; kc += 128) {
    __syncthreads();
    {
      int row = t >> 4, c8 = (t & 15) * 8;
      *(uint4*)&xl[row][c8] = *(const uint4*)(xb + (size_t)(b*NT + kid[row]) * ND + kc + c8);
    }
    __syncthreads();
    #pragma unroll 1
    for (int sub = 0; sub < 8; ++sub) {
      s16x8 k0 = *(const s16x8*)(wkr + kc + sub*16);
      s16x8 k1 = *(const s16x8*)(wkr + kc + sub*16 + 8);
      s16x8 v0 = *(const s16x8*)(wvr + kc + sub*16);
      s16x8 v1 = *(const s16x8*)(wvr + kc + sub*16 + 8);
      float kf[16], vf2[16];
      #pragma unroll
      for (int j = 0; j < 8; ++j) {
        kf[j]  = bf2f((ushort)k0[j]); kf[8+j]  = bf2f((ushort)k1[j]);
        vf2[j] = bf2f((ushort)v0[j]); vf2[8+j] = bf2f((ushort)v1[j]);
      }
      #pragma unroll
      for (int kk = 0; kk < 4; ++kk) {
        #pragma unroll
        for (int j = 0; j < 16; ++j) {
          float xvv = bf2f(xl[kq*4 + kk][sub*16 + j]);
          ak[kk] += xvv * kf[j];
          av[kk] += xvv * vf2[j];
        }
      }
    }
  }
  #pragma unroll
  for (int kk = 0; kk < 4; ++kk) {
    int key = gy*16 + kq*4 + kk;
    ksp[((size_t)bh*NK + key)*NHD + d] = f2bf(ak[kk]);
    vtsp[((size_t)bh*NHD + d)*NK + key] = f2bf(av[kk]);   // transposed for PV B-frags
  }
}

// ---- m97-structure NT GEMM: C[M,N] = A[M,K](bf16) * B[N,K]^T(bf16) ----
template<int STORE_BF16>
__global__ __launch_bounds__(256) void gemm_nt_kernel(
    const ushort* __restrict__ A, const ushort* __restrict__ Bw,
    void* __restrict__ Cout, int M, int N, int K) {
  __shared__ __align__(16) ushort As[2][4096];
  __shared__ __align__(16) ushort Bs[2][4096];
  int nbn = N >> 7;
  int nwg = (M >> 7) * nbn;
  int bid = blockIdx.x;
  int qq = nwg >> 3;                       // nwg % 8 == 0 for our shapes
  int wg = (bid & 7) * qq + (bid >> 3);    // XCD-aware swizzle
  int tm = wg / nbn, tn = wg % nbn;
  int t = threadIdx.x, w = t >> 6, l = t & 63;
  int wm = (w >> 1) * 64, wn = (w & 1) * 64;
  const ushort* Abase = A + (size_t)tm * 128 * K;
  const ushort* Bbase = Bw + (size_t)tn * 128 * K;
  int row0 = t >> 2, c8 = (t & 3) * 8;
  int row1 = (256 + t) >> 2;
  f32x4 acc[4][4];
  #pragma unroll
  for (int i = 0; i < 4; ++i)
    #pragma unroll
    for (int j = 0; j < 4; ++j)
      #pragma unroll
      for (int r = 0; r < 4; ++r) acc[i][j][r] = 0.f;

  #define STAGE(buf, kk) do { \
    __builtin_amdgcn_global_load_lds((gas1_t)(Abase + (size_t)row0*K + (kk) + c8), (las3_t)&As[buf][(w*64)*8], 16, 0, 0); \
    __builtin_amdgcn_global_load_lds((gas1_t)(Abase + (size_t)row1*K + (kk) + c8), (las3_t)&As[buf][(256 + w*64)*8], 16, 0, 0); \
    __builtin_amdgcn_global_load_lds((gas1_t)(Bbase + (size_t)row0*K + (kk) + c8), (las3_t)&Bs[buf][(w*64)*8], 16, 0, 0); \
    __builtin_amdgcn_global_load_lds((gas1_t)(Bbase + (size_t)row1*K + (kk) + c8), (las3_t)&Bs[buf][(256 + w*64)*8], 16, 0, 0); \
  } while (0)

  STAGE(0, 0);
  __syncthreads();
  int nk = K >> 5;
  int aoff = (l & 15) * 32 + (l >> 4) * 8;
  for (int kt = 0; kt < nk; ++kt) {
    int cur = kt & 1;
    if (kt + 1 < nk) STAGE(cur ^ 1, (kt + 1) * 32);
    s16x8 af[4], bfr[4];
    #pragma unroll
    for (int mi = 0; mi < 4; ++mi) af[mi] = *(const s16x8*)&As[cur][(wm + mi*16)*32 + aoff];
    #pragma unroll
    for (int ni = 0; ni < 4; ++ni) bfr[ni] = *(const s16x8*)&Bs[cur][(wn + ni*16)*32 + aoff];
    #pragma unroll
    for (int mi = 0; mi < 4; ++mi)
      #pragma unroll
      for (int ni = 0; ni < 4; ++ni)
        acc[mi][ni] = __builtin_amdgcn_mfma_f32_16x16x32_bf16(af[mi], bfr[ni], acc[mi][ni], 0, 0, 0);
    __syncthreads();
  }
  #undef STAGE
  int grow = tm*128 + wm + (l >> 4) * 4;
  int gcol = tn*128 + wn + (l & 15);
  #pragma unroll
  for (int mi = 0; mi < 4; ++mi)
    #pragma unroll
    for (int ni = 0; ni < 4; ++ni)
      #pragma unroll
      for (int r = 0; r < 4; ++r) {
        size_t off = (size_t)(grow + mi*16 + r) * N + gcol + ni*16;
        if (STORE_BF16) ((ushort*)Cout)[off] = f2bf(acc[mi][ni][r]);
        else            ((float*)Cout)[off]  = acc[mi][ni][r];
      }
}

// ---- attention vs 64 keys: per-wave 64 q-rows; K/V frags live in registers ----
__global__ __launch_bounds__(256) void attn_kernel(
    const ushort* __restrict__ qg, const ushort* __restrict__ ksp,
    const ushort* __restrict__ vtsp, ushort* __restrict__ aout) {
  int bh = blockIdx.y;
  int b = bh >> 4, h = bh & 15;
  int t = threadIdx.x, w = t >> 6, l = t & 63;
  __shared__ __align__(16) ushort Pl[4][1024];   // per-wave 16x64 P tile (XOR-swizzled)
  const ushort* kb = ksp + (size_t)bh * NK * NHD;
  const ushort* vb = vtsp + (size_t)bh * NHD * NK;
  s16x8 kf[2][4], vf[2][4];
  #pragma unroll
  for (int ks = 0; ks < 2; ++ks)
    #pragma unroll
    for (int ni = 0; ni < 4; ++ni) {
      kf[ks][ni] = *(const s16x8*)&kb[(size_t)(ni*16 + (l & 15))*NHD + ks*32 + (l >> 4)*8];
      vf[ks][ni] = *(const s16x8*)&vb[(size_t)(ni*16 + (l & 15))*NK + ks*32 + (l >> 4)*8];
    }
  int rowbase = blockIdx.x * 256 + w * 64;
  #pragma unroll 1
  for (int mi = 0; mi < 4; ++mi) {
    int r0 = rowbase + mi * 16;
    s16x8 af[2];
    #pragma unroll
    for (int ks = 0; ks < 2; ++ks)
      af[ks] = *(const s16x8*)&qg[(size_t)(b*NT + r0 + (l & 15))*ND + h*NHD + ks*32 + (l >> 4)*8];
    f32x4 sc[4];
    #pragma unroll
    for (int ni = 0; ni < 4; ++ni) {
      f32x4 z; z[0]=0.f; z[1]=0.f; z[2]=0.f; z[3]=0.f;
      z = __builtin_amdgcn_mfma_f32_16x16x32_bf16(af[0], kf[0][ni], z, 0, 0, 0);
      sc[ni] = __builtin_amdgcn_mfma_f32_16x16x32_bf16(af[1], kf[1][ni], z, 0, 0, 0);
    }
    #pragma unroll
    for (int r = 0; r < 4; ++r) {
      float v0 = sc[0][r]*0.125f, v1 = sc[1][r]*0.125f;
      float v2 = sc[2][r]*0.125f, v3 = sc[3][r]*0.125f;
      float m = fmaxf(fmaxf(v0, v1), fmaxf(v2, v3));
      #pragma unroll
      for (int mm = 8; mm >= 1; mm >>= 1) m = fmaxf(m, __shfl_xor(m, mm, 64));
      float e0 = __expf(v0 - m), e1 = __expf(v1 - m);
      float e2 = __expf(v2 - m), e3 = __expf(v3 - m);
      float s = e0 + e1 + e2 + e3;
      #pragma unroll
      for (int mm = 8; mm >= 1; mm >>= 1) s += __shfl_xor(s, mm, 64);
      float inv = 1.f / s;
      int prow = (l >> 4)*4 + r;
      int lo = l & 7, hb = (l >> 3) & 1, sw = prow & 7;
      Pl[w][prow*64 + ((0 + hb) ^ sw)*8 + lo] = f2bf(e0 * inv);
      Pl[w][prow*64 + ((2 + hb) ^ sw)*8 + lo] = f2bf(e1 * inv);
      Pl[w][prow*64 + ((4 + hb) ^ sw)*8 + lo] = f2bf(e2 * inv);
      Pl[w][prow*64 + ((6 + hb) ^ sw)*8 + lo] = f2bf(e3 * inv);
    }
    s16x8 pf[2];
    #pragma unroll
    for (int ks = 0; ks < 2; ++ks)
      pf[ks] = *(const s16x8*)&Pl[w][(l & 15)*64 + ((ks*4 + (l >> 4)) ^ (l & 7))*8];
    f32x4 oc[4];
    #pragma unroll
    for (int ni = 0; ni < 4; ++ni) {
      f32x4 z; z[0]=0.f; z[1]=0.f; z[2]=0.f; z[3]=0.f;
      z = __builtin_amdgcn_mfma_f32_16x16x32_bf16(pf[0], vf[0][ni], z, 0, 0, 0);
      oc[ni] = __builtin_amdgcn_mfma_f32_16x16x32_bf16(pf[1], vf[1][ni], z, 0, 0, 0);
    }
    #pragma unroll
    for (int ni = 0; ni < 4; ++ni)
      #pragma unroll
      for (int r = 0; r < 4; ++r) {
        int row = r0 + (l >> 4)*4 + r;
        aout[(size_t)(b*NT + row)*ND + h*NHD + ni*16 + (l & 15)] = f2bf(oc[ni][r]);
      }
  }
}

extern "C" void kernel_launch(void* const* d_in, const int* in_sizes, int n_in,
                              void* d_out, int out_size, void* d_ws, size_t ws_size,
                              hipStream_t stream) {
  (void)in_sizes; (void)n_in; (void)out_size; (void)ws_size;
  const float* x  = (const float*)d_in[0];
  const float* Wq = (const float*)d_in[1];
  const float* Wk = (const float*)d_in[2];
  const float* Wv = (const float*)d_in[3];
  const float* Wo = (const float*)d_in[4];
  const float* wscore = (const float*)d_in[5];

  char* base = (char*)d_ws;
  ushort* xb     = (ushort*)(base + 0);           // 64 MiB  (reused as attn out)
  ushort* qb     = (ushort*)(base + 67108864);    // 64 MiB
  float*  scores = (float*) (base + 134217728);   // 2 MiB
  float*  u      = (float*) (base + 136314880);   // 64 KiB
  ushort* wqb    = (ushort*)(base + 136380416);   // 2 MiB
  ushort* wkb    = (ushort*)(base + 138477568);   // 2 MiB
  ushort* wvb    = (ushort*)(base + 140574720);   // 2 MiB
  ushort* wob    = (ushort*)(base + 142671872);   // 2 MiB
  int*    tidx   = (int*)   (base + 144769024);   // 16 KiB
  ushort* ksp    = (ushort*)(base + 144785408);   // 512 KiB
  ushort* vtsp   = (ushort*)(base + 145309696);   // 512 KiB
  ushort* aout   = xb;   // xb is dead after gemm_q + sparse_kv

  convert_w_kernel<<<dim3(4096), dim3(256), 0, stream>>>(Wq, Wk, Wv, Wo, wqb, wkb, wvb, wob);
  prep_u_kernel<<<dim3(64), dim3(256), 0, stream>>>(Wk, wscore, u);
  prep_x_kernel<<<dim3(1024), dim3(256), 0, stream>>>(x, u, xb, scores);
  topk_kernel<<<dim3(64), dim3(256), 0, stream>>>(scores, tidx);
  sparse_kv_kernel<<<dim3(64, 4), dim3(256), 0, stream>>>(xb, wkb, wvb, tidx, ksp, vtsp);
  gemm_nt_kernel<1><<<dim3(2048), dim3(256), 0, stream>>>(xb, wqb, (void*)qb, NM, ND, ND);
  attn_kernel<<<dim3(32, 64), dim3(256), 0, stream>>>(qb, ksp, vtsp, aout);
  gemm_nt_kernel<0><<<dim3(2048), dim3(256), 0, stream>>>(aout, wob, d_out, NM, ND, ND);
}

// Round 4
// 312.936 us; speedup vs baseline: 1.6319x; 1.0806x over previous
//
#include <hip/hip_runtime.h>
#include <hip/hip_bf16.h>
#include <stdint.h>

#define NB 4
#define NT 8192
#define ND 1024
#define NH 16
#define NHD 64
#define NK 64        // top-k
#define NM (NB*NT)   // 32768

typedef __attribute__((ext_vector_type(4))) float f32x4;
typedef __attribute__((ext_vector_type(8))) short s16x8;
typedef const void __attribute__((address_space(1)))* gas1_t;
typedef void __attribute__((address_space(3)))* las3_t;

__device__ __forceinline__ float bf2f(ushort u) {
  union { uint32_t i; float f; } v; v.i = ((uint32_t)u) << 16; return v.f;
}
__device__ __forceinline__ ushort f2bf(float f) {
  union { float f; uint32_t i; } v; v.f = f;
  uint32_t r = v.i + 0x7FFFu + ((v.i >> 16) & 1u);
  return (ushort)(r >> 16);
}
__device__ __forceinline__ uint32_t f2ord(uint32_t u) {
  return (u & 0x80000000u) ? ~u : (u | 0x80000000u);
}

// ---- convert the four weight matrices to bf16 ----
__global__ __launch_bounds__(256) void convert_w_kernel(
    const float* __restrict__ Wq, const float* __restrict__ Wk,
    const float* __restrict__ Wv, const float* __restrict__ Wo,
    ushort* __restrict__ wqb, ushort* __restrict__ wkb,
    ushort* __restrict__ wvb, ushort* __restrict__ wob) {
  int i = blockIdx.x * 256 + threadIdx.x;   // grid covers exactly 1M
  wqb[i] = f2bf(Wq[i]); wkb[i] = f2bf(Wk[i]);
  wvb[i] = f2bf(Wv[i]); wob[i] = f2bf(Wo[i]);
}

// ---- u[h][e] = sum_d wscore[d] * Wk[h*64+d][e]  (fp32, exact path for topk) ----
__global__ __launch_bounds__(256) void prep_u_kernel(
    const float* __restrict__ Wk, const float* __restrict__ wscore,
    float* __restrict__ u) {
  int e = (blockIdx.x & 3) * 256 + threadIdx.x;
  int h = blockIdx.x >> 2;
  float acc = 0.f;
  #pragma unroll 8
  for (int d = 0; d < NHD; ++d) acc += wscore[d] * Wk[(size_t)(h*NHD + d)*ND + e];
  u[h*ND + e] = acc;
}

// ---- x -> bf16, and fp32 indexer scores[b*16+h][t] = x_row . u[h] ----
// u lives in VGPRs (lane owns u[0..15][its 4 elems]); packed butterfly reduce.
__global__ __launch_bounds__(256) void prep_x_kernel(
    const float* __restrict__ x, const float* __restrict__ u,
    ushort* __restrict__ xb, float* __restrict__ scores) {
  __shared__ float pbuf[16][4][17];   // [row-in-batch][wave][h], padded
  int t = threadIdx.x, w = t >> 6, l = t & 63;
  int e0 = w * 256 + l * 4;           // this lane's 4-elem slice of the row
  float4 uv[16];
  #pragma unroll
  for (int h = 0; h < 16; ++h) uv[h] = *(const float4*)(u + h * ND + e0);
  int row0 = blockIdx.x * 32;
  int boff = ((row0 >> 13) << 4);      // b*16
  int tt0 = row0 & (NT - 1);
  for (int batch = 0; batch < 2; ++batch) {   // 2 batches of 16 rows
    #pragma unroll 2
    for (int rr = 0; rr < 16; ++rr) {
      int row = row0 + batch * 16 + rr;
      float4 xv = *(const float4*)(x + (size_t)row * ND + e0);
      ushort4 o; o.x = f2bf(xv.x); o.y = f2bf(xv.y); o.z = f2bf(xv.z); o.w = f2bf(xv.w);
      *(ushort4*)(xb + (size_t)row * ND + e0) = o;
      float p[16];
      #pragma unroll
      for (int h = 0; h < 16; ++h)
        p[h] = xv.x*uv[h].x + xv.y*uv[h].y + xv.z*uv[h].z + xv.w*uv[h].w;
      float q8[8];
      #pragma unroll
      for (int j = 0; j < 8; ++j) {
        bool hi = (l & 1);
        float keep = hi ? p[2*j+1] : p[2*j];
        float send = hi ? p[2*j]   : p[2*j+1];
        q8[j] = keep + __shfl_xor(send, 1, 64);
      }
      float q4[4];
      #pragma unroll
      for (int j = 0; j < 4; ++j) {
        bool hi = ((l >> 1) & 1);
        float keep = hi ? q8[2*j+1] : q8[2*j];
        float send = hi ? q8[2*j]   : q8[2*j+1];
        q4[j] = keep + __shfl_xor(send, 2, 64);
      }
      float q2[2];
      #pragma unroll
      for (int j = 0; j < 2; ++j) {
        bool hi = ((l >> 2) & 1);
        float keep = hi ? q4[2*j+1] : q4[2*j];
        float send = hi ? q4[2*j]   : q4[2*j+1];
        q2[j] = keep + __shfl_xor(send, 4, 64);
      }
      float q1;
      {
        bool hi = ((l >> 3) & 1);
        float keep = hi ? q2[1] : q2[0];
        float send = hi ? q2[0] : q2[1];
        q1 = keep + __shfl_xor(send, 8, 64);
      }
      q1 += __shfl_xor(q1, 16, 64);
      q1 += __shfl_xor(q1, 32, 64);
      if (l < 16) pbuf[rr][w][l] = q1;   // h = l&15
    }
    __syncthreads();
    {
      int r16 = t & 15, h = t >> 4;      // consecutive t -> consecutive tt (coalesced)
      float s = pbuf[r16][0][h] + pbuf[r16][1][h] + pbuf[r16][2][h] + pbuf[r16][3][h];
      scores[(size_t)(boff + h) * NT + tt0 + batch * 16 + r16] = s;
    }
    __syncthreads();
  }
}

// ---- top-64 per (b,h) via single-pass radix-select (12-bit histogram) ----
__global__ __launch_bounds__(256) void topk_kernel(
    const float* __restrict__ scores, int* __restrict__ tidx) {
  int bh = blockIdx.x, t = threadIdx.x;
  __shared__ uint32_t keys[NT];      // 32 KiB order-preserving keys
  __shared__ int hist[4096];         // 16 KiB
  __shared__ uint32_t ck[512];
  __shared__ int ci[512];
  __shared__ int chunksum[256];
  __shared__ int s_binB, s_c0;
  __shared__ int cnt_hi, cnt_cand;

  for (int i = t; i < 4096; i += 256) hist[i] = 0;
  if (t == 0) { cnt_hi = 0; cnt_cand = 0; }
  __syncthreads();
  const uint4* sg = (const uint4*)(scores + (size_t)bh * NT);
  for (int i = t; i < NT/4; i += 256) {
    uint4 v = sg[i];
    uint32_t k0 = f2ord(v.x), k1 = f2ord(v.y), k2 = f2ord(v.z), k3 = f2ord(v.w);
    keys[i*4+0] = k0; keys[i*4+1] = k1; keys[i*4+2] = k2; keys[i*4+3] = k3;
    atomicAdd(&hist[k0 >> 20], 1); atomicAdd(&hist[k1 >> 20], 1);
    atomicAdd(&hist[k2 >> 20], 1); atomicAdd(&hist[k3 >> 20], 1);
  }
  __syncthreads();
  {
    int hi = 4095 - t * 16;
    int s = 0;
    #pragma unroll
    for (int j = 0; j < 16; ++j) s += hist[hi - j];
    chunksum[t] = s;
  }
  __syncthreads();
  if (t == 0) {
    int cum = 0, c = 0;
    while (cum + chunksum[c] < NK) { cum += chunksum[c]; ++c; }
    int bin = 4095 - c * 16;
    while (cum + hist[bin] < NK) { cum += hist[bin]; --bin; }
    s_binB = bin; s_c0 = cum;
  }
  __syncthreads();
  int binB = s_binB, c0 = s_c0;
  for (int i = t; i < NT; i += 256) {
    int b = keys[i] >> 20;
    if (b > binB) {
      int p = atomicAdd(&cnt_hi, 1);
      tidx[bh*NK + p] = i;
    } else if (b == binB) {
      int p = atomicAdd(&cnt_cand, 1);
      if (p < 512) { ck[p] = keys[i]; ci[p] = i; }
    }
  }
  __syncthreads();
  int nc = cnt_cand; if (nc > 512) nc = 512;
  int need = NK - c0;
  for (int p = t; p < nc; p += 256) {
    uint32_t myk = ck[p]; int myi = ci[p];
    int rank = 0;
    for (int j = 0; j < nc; ++j) {
      uint32_t kj = ck[j];
      rank += (kj > myk || (kj == myk && ci[j] < myi)) ? 1 : 0;
    }
    if (rank < need) tidx[bh*NK + c0 + rank] = myi;
  }
}

// ---- project ONLY the 64 selected rows per (b,h) into K_sp[key][d], V^T_sp[d][key] ----
__global__ __launch_bounds__(256) void sparse_kv_kernel(
    const ushort* __restrict__ xb, const ushort* __restrict__ wkb,
    const ushort* __restrict__ wvb, const int* __restrict__ tidx,
    ushort* __restrict__ ksp, ushort* __restrict__ vtsp) {
  int bh = blockIdx.x, gy = blockIdx.y;
  int b = bh >> 4, h = bh & 15;
  int t = threadIdx.x;
  __shared__ __align__(16) ushort xl[16][128];
  __shared__ int kid[16];
  if (t < 16) kid[t] = tidx[bh*NK + gy*16 + t];
  int d = t & 63, kq = t >> 6;
  float ak[4] = {0.f,0.f,0.f,0.f}, av[4] = {0.f,0.f,0.f,0.f};
  const ushort* wkr = wkb + (size_t)(h*NHD + d) * ND;
  const ushort* wvr = wvb + (size_t)(h*NHD + d) * ND;
  for (int kc = 0; kc < ND; kc += 128) {
    __syncthreads();
    {
      int row = t >> 4, c8 = (t & 15) * 8;
      *(uint4*)&xl[row][c8] = *(const uint4*)(xb + (size_t)(b*NT + kid[row]) * ND + kc + c8);
    }
    __syncthreads();
    #pragma unroll 1
    for (int sub = 0; sub < 8; ++sub) {
      s16x8 k0 = *(const s16x8*)(wkr + kc + sub*16);
      s16x8 k1 = *(const s16x8*)(wkr + kc + sub*16 + 8);
      s16x8 v0 = *(const s16x8*)(wvr + kc + sub*16);
      s16x8 v1 = *(const s16x8*)(wvr + kc + sub*16 + 8);
      float kf[16], vf2[16];
      #pragma unroll
      for (int j = 0; j < 8; ++j) {
        kf[j]  = bf2f((ushort)k0[j]); kf[8+j]  = bf2f((ushort)k1[j]);
        vf2[j] = bf2f((ushort)v0[j]); vf2[8+j] = bf2f((ushort)v1[j]);
      }
      #pragma unroll
      for (int kk = 0; kk < 4; ++kk) {
        #pragma unroll
        for (int j = 0; j < 16; ++j) {
          float xvv = bf2f(xl[kq*4 + kk][sub*16 + j]);
          ak[kk] += xvv * kf[j];
          av[kk] += xvv * vf2[j];
        }
      }
    }
  }
  #pragma unroll
  for (int kk = 0; kk < 4; ++kk) {
    int key = gy*16 + kq*4 + kk;
    ksp[((size_t)bh*NK + key)*NHD + d] = f2bf(ak[kk]);
    vtsp[((size_t)bh*NHD + d)*NK + key] = f2bf(av[kk]);
  }
}

// ==== 256x256 8-phase GEMM (T2+T3+T4+T5): C[M,N]=A[M,K]@Bw[N,K]^T ====
// M=32768, N=K=1024 fixed. BM=BN=256, BK=64, 8 waves (2Mx4N), 128KiB LDS.
// LDS tile layout (A and B identical): [kk-half][row 0..255][32 kh], with
// XOR swizzle kh_slot = kh ^ (((row>>3)&1)<<4), applied on BOTH the staged
// global source address and the ds_read offset (involution, rule 21).
template<int STORE_BF16>
__global__ __launch_bounds__(512, 2) void gemm8_kernel(
    const ushort* __restrict__ A, const ushort* __restrict__ Bw,
    void* __restrict__ Cout) {
  __shared__ __align__(16) char lds[131072];
  const int t = threadIdx.x, wid = t >> 6, l = t & 63;
  const int wr = wid >> 2, wc = wid & 3;
  int bid = blockIdx.x;                  // nwg = 512 = 8 XCD * 64
  int wg = (bid & 7) * 64 + (bid >> 3);  // XCD swizzle (bijective, 512%8==0)
  int tm = wg >> 2, tn = wg & 3;
  const int K = 1024, N = 1024;
  const ushort* Ab = A + (size_t)tm * 256 * K;
  const ushort* Bb = Bw + (size_t)tn * 256 * K;
  // staging: lane covers row (l>>2) of its wave's 16-row stripe, 8 k-elems
  const int skh  = ((l & 3) * 8) ^ (((l >> 5) & 1) << 4);  // pre-swizzled src k
  const int srow = l >> 2;
  // ds_read: lane reads frag row base+(l&15), logical kh=(l>>4)*8, swizzled
  const int lane_off = (l & 15) * 64 + ((((l >> 4) * 8) ^ (((l >> 3) & 1) << 4)) * 2);
  f32x4 acc[8][4];
  #pragma unroll
  for (int i = 0; i < 8; ++i)
    #pragma unroll
    for (int j = 0; j < 4; ++j) acc[i][j] = (f32x4){0.f, 0.f, 0.f, 0.f};
  s16x8 afr[4][2], bfr[2][2];

#define STG(gbase, matoff, half, ktile, buf) do { \
    const ushort* _s = (gbase) + (size_t)((half)*128 + wid*16 + srow) * K + (ktile)*64 + skh; \
    int _d = (buf)*65536 + (matoff) + ((half)*128 + wid*16)*64; \
    __builtin_amdgcn_global_load_lds((gas1_t)_s, (las3_t)(lds + _d), 16, 0, 0); \
    __builtin_amdgcn_global_load_lds((gas1_t)(_s + 32), (las3_t)(lds + _d + 16384), 16, 0, 0); \
  } while (0)

#define LDA(mh, buf) do { \
    _Pragma("unroll") \
    for (int mi = 0; mi < 4; ++mi) { \
      int _r = (buf)*65536 + (((mh)*2 + wr)*64 + mi*16)*64 + lane_off; \
      afr[mi][0] = *(const s16x8*)(lds + _r); \
      afr[mi][1] = *(const s16x8*)(lds + _r + 16384); \
    } } while (0)

#define LDB(nh, buf) do { \
    _Pragma("unroll") \
    for (int ni = 0; ni < 2; ++ni) { \
      int _r = (buf)*65536 + 32768 + (((nh)*128 + wc*32 + ni*16))*64 + lane_off; \
      bfr[ni][0] = *(const s16x8*)(lds + _r); \
      bfr[ni][1] = *(const s16x8*)(lds + _r + 16384); \
    } } while (0)

#define MMAQ(mh, nh) do { \
    __builtin_amdgcn_s_setprio(1); \
    _Pragma("unroll") \
    for (int mi = 0; mi < 4; ++mi) \
      _Pragma("unroll") \
      for (int ni = 0; ni < 2; ++ni) { \
        f32x4 _a = acc[(mh)*4+mi][(nh)*2+ni]; \
        _a = __builtin_amdgcn_mfma_f32_16x16x32_bf16(afr[mi][0], bfr[ni][0], _a, 0, 0, 0); \
        _a = __builtin_amdgcn_mfma_f32_16x16x32_bf16(afr[mi][1], bfr[ni][1], _a, 0, 0, 0); \
        acc[(mh)*4+mi][(nh)*2+ni] = _a; \
      } \
    __builtin_amdgcn_s_setprio(0); \
  } while (0)

#define BAR() __builtin_amdgcn_s_barrier()
#define LGKM0() do { asm volatile("s_waitcnt lgkmcnt(0)" ::: "memory"); \
                     __builtin_amdgcn_sched_barrier(0); } while (0)

  // prologue: tile0 {A0,B1,A1,B0} + tile1 {A0,B1,A1}; wait tile0 (leave 3 in flight)
  STG(Ab, 0,     0, 0, 0);
  STG(Bb, 32768, 1, 0, 0);
  STG(Ab, 0,     1, 0, 0);
  STG(Bb, 32768, 0, 0, 0);
  STG(Ab, 0,     0, 1, 1);
  STG(Bb, 32768, 1, 1, 1);
  STG(Ab, 0,     1, 1, 1);
  asm volatile("s_waitcnt vmcnt(6)" ::: "memory");
  BAR();

  // ledger per tile kt (steady state): issue {B0(kt+1), A0(kt+2), B1(kt+2),
  // A1(kt+2)} at phases 1-4; vmcnt(6) at ph4 completes tile kt+1 exactly.
#define TILE(kt, bc, bn) do { \
    /* ph1: quadrant (mh0,nh0) */ \
    LDA(0, bc); LDB(0, bc); \
    if ((kt) + 1 < 16) STG(Bb, 32768, 0, (kt)+1, bn); \
    BAR(); LGKM0(); MMAQ(0, 0); BAR(); \
    /* ph2: (mh0,nh1) */ \
    LDB(1, bc); \
    if ((kt) + 2 < 16) STG(Ab, 0, 0, (kt)+2, bc); \
    BAR(); LGKM0(); MMAQ(0, 1); BAR(); \
    /* ph3: (mh1,nh1) */ \
    LDA(1, bc); \
    if ((kt) + 2 < 16) STG(Bb, 32768, 1, (kt)+2, bc); \
    BAR(); LGKM0(); MMAQ(1, 1); BAR(); \
    /* ph4: (mh1,nh0), B0 re-read */ \
    LDB(0, bc); \
    if ((kt) + 2 < 16) STG(Ab, 0, 1, (kt)+2, bc); \
    BAR(); LGKM0(); MMAQ(1, 0); \
    if ((kt) < 14)       { asm volatile("s_waitcnt vmcnt(6)" ::: "memory"); } \
    else if ((kt) == 14) { asm volatile("s_waitcnt vmcnt(0)" ::: "memory"); } \
    BAR(); \
  } while (0)

  for (int k2 = 0; k2 < 8; ++k2) {
    TILE(2*k2,     0, 1);
    TILE(2*k2 + 1, 1, 0);
  }
#undef TILE
#undef STG
#undef LDA
#undef LDB
#undef MMAQ
#undef BAR
#undef LGKM0

  // epilogue: C/D layout col=l&15, row=(l>>4)*4+r
  #pragma unroll
  for (int mi8 = 0; mi8 < 8; ++mi8) {
    int grow = tm*256 + (((mi8 >> 2)*2 + wr)*64) + (mi8 & 3)*16 + (l >> 4)*4;
    #pragma unroll
    for (int ni4 = 0; ni4 < 4; ++ni4) {
      int gcol = tn*256 + (ni4 >> 1)*128 + wc*32 + (ni4 & 1)*16 + (l & 15);
      #pragma unroll
      for (int r = 0; r < 4; ++r) {
        size_t off = (size_t)(grow + r) * N + gcol;
        if (STORE_BF16) ((ushort*)Cout)[off] = f2bf(acc[mi8][ni4][r]);
        else            ((float*)Cout)[off]  = acc[mi8][ni4][r];
      }
    }
  }
}

// ---- attention vs 64 keys: per-wave 64 q-rows; K/V frags live in registers ----
__global__ __launch_bounds__(256) void attn_kernel(
    const ushort* __restrict__ qg, const ushort* __restrict__ ksp,
    const ushort* __restrict__ vtsp, ushort* __restrict__ aout) {
  int bh = blockIdx.y;
  int b = bh >> 4, h = bh & 15;
  int t = threadIdx.x, w = t >> 6, l = t & 63;
  __shared__ __align__(16) ushort Pl[4][1024];
  const ushort* kb = ksp + (size_t)bh * NK * NHD;
  const ushort* vb = vtsp + (size_t)bh * NHD * NK;
  s16x8 kf[2][4], vf[2][4];
  #pragma unroll
  for (int ks = 0; ks < 2; ++ks)
    #pragma unroll
    for (int ni = 0; ni < 4; ++ni) {
      kf[ks][ni] = *(const s16x8*)&kb[(size_t)(ni*16 + (l & 15))*NHD + ks*32 + (l >> 4)*8];
      vf[ks][ni] = *(const s16x8*)&vb[(size_t)(ni*16 + (l & 15))*NK + ks*32 + (l >> 4)*8];
    }
  int rowbase = blockIdx.x * 256 + w * 64;
  #pragma unroll 1
  for (int mi = 0; mi < 4; ++mi) {
    int r0 = rowbase + mi * 16;
    s16x8 af[2];
    #pragma unroll
    for (int ks = 0; ks < 2; ++ks)
      af[ks] = *(const s16x8*)&qg[(size_t)(b*NT + r0 + (l & 15))*ND + h*NHD + ks*32 + (l >> 4)*8];
    f32x4 sc[4];
    #pragma unroll
    for (int ni = 0; ni < 4; ++ni) {
      f32x4 z; z[0]=0.f; z[1]=0.f; z[2]=0.f; z[3]=0.f;
      z = __builtin_amdgcn_mfma_f32_16x16x32_bf16(af[0], kf[0][ni], z, 0, 0, 0);
      sc[ni] = __builtin_amdgcn_mfma_f32_16x16x32_bf16(af[1], kf[1][ni], z, 0, 0, 0);
    }
    #pragma unroll
    for (int r = 0; r < 4; ++r) {
      float v0 = sc[0][r]*0.125f, v1 = sc[1][r]*0.125f;
      float v2 = sc[2][r]*0.125f, v3 = sc[3][r]*0.125f;
      float m = fmaxf(fmaxf(v0, v1), fmaxf(v2, v3));
      #pragma unroll
      for (int mm = 8; mm >= 1; mm >>= 1) m = fmaxf(m, __shfl_xor(m, mm, 64));
      float e0 = __expf(v0 - m), e1 = __expf(v1 - m);
      float e2 = __expf(v2 - m), e3 = __expf(v3 - m);
      float s = e0 + e1 + e2 + e3;
      #pragma unroll
      for (int mm = 8; mm >= 1; mm >>= 1) s += __shfl_xor(s, mm, 64);
      float inv = 1.f / s;
      int prow = (l >> 4)*4 + r;
      int lo = l & 7, hb = (l >> 3) & 1, sw = prow & 7;
      Pl[w][prow*64 + ((0 + hb) ^ sw)*8 + lo] = f2bf(e0 * inv);
      Pl[w][prow*64 + ((2 + hb) ^ sw)*8 + lo] = f2bf(e1 * inv);
      Pl[w][prow*64 + ((4 + hb) ^ sw)*8 + lo] = f2bf(e2 * inv);
      Pl[w][prow*64 + ((6 + hb) ^ sw)*8 + lo] = f2bf(e3 * inv);
    }
    s16x8 pf[2];
    #pragma unroll
    for (int ks = 0; ks < 2; ++ks)
      pf[ks] = *(const s16x8*)&Pl[w][(l & 15)*64 + ((ks*4 + (l >> 4)) ^ (l & 7))*8];
    f32x4 oc[4];
    #pragma unroll
    for (int ni = 0; ni < 4; ++ni) {
      f32x4 z; z[0]=0.f; z[1]=0.f; z[2]=0.f; z[3]=0.f;
      z = __builtin_amdgcn_mfma_f32_16x16x32_bf16(pf[0], vf[0][ni], z, 0, 0, 0);
      oc[ni] = __builtin_amdgcn_mfma_f32_16x16x32_bf16(pf[1], vf[1][ni], z, 0, 0, 0);
    }
    #pragma unroll
    for (int ni = 0; ni < 4; ++ni)
      #pragma unroll
      for (int r = 0; r < 4; ++r) {
        int row = r0 + (l >> 4)*4 + r;
        aout[(size_t)(b*NT + row)*ND + h*NHD + ni*16 + (l & 15)] = f2bf(oc[ni][r]);
      }
  }
}

extern "C" void kernel_launch(void* const* d_in, const int* in_sizes, int n_in,
                              void* d_out, int out_size, void* d_ws, size_t ws_size,
                              hipStream_t stream) {
  (void)in_sizes; (void)n_in; (void)out_size; (void)ws_size;
  const float* x  = (const float*)d_in[0];
  const float* Wq = (const float*)d_in[1];
  const float* Wk = (const float*)d_in[2];
  const float* Wv = (const float*)d_in[3];
  const float* Wo = (const float*)d_in[4];
  const float* wscore = (const float*)d_in[5];

  char* base = (char*)d_ws;
  ushort* xb     = (ushort*)(base + 0);           // 64 MiB  (reused as attn out)
  ushort* qb     = (ushort*)(base + 67108864);    // 64 MiB
  float*  scores = (float*) (base + 134217728);   // 2 MiB
  float*  u      = (float*) (base + 136314880);   // 64 KiB
  ushort* wqb    = (ushort*)(base + 136380416);   // 2 MiB
  ushort* wkb    = (ushort*)(base + 138477568);   // 2 MiB
  ushort* wvb    = (ushort*)(base + 140574720);   // 2 MiB
  ushort* wob    = (ushort*)(base + 142671872);   // 2 MiB
  int*    tidx   = (int*)   (base + 144769024);   // 16 KiB
  ushort* ksp    = (ushort*)(base + 144785408);   // 512 KiB
  ushort* vtsp   = (ushort*)(base + 145309696);   // 512 KiB
  ushort* aout   = xb;   // xb is dead after gemm_q + sparse_kv

  convert_w_kernel<<<dim3(4096), dim3(256), 0, stream>>>(Wq, Wk, Wv, Wo, wqb, wkb, wvb, wob);
  prep_u_kernel<<<dim3(64), dim3(256), 0, stream>>>(Wk, wscore, u);
  prep_x_kernel<<<dim3(1024), dim3(256), 0, stream>>>(x, u, xb, scores);
  topk_kernel<<<dim3(64), dim3(256), 0, stream>>>(scores, tidx);
  sparse_kv_kernel<<<dim3(64, 4), dim3(256), 0, stream>>>(xb, wkb, wvb, tidx, ksp, vtsp);
  gemm8_kernel<1><<<dim3(512), dim3(512), 0, stream>>>(xb, wqb, (void*)qb);
  attn_kernel<<<dim3(32, 64), dim3(256), 0, stream>>>(qb, ksp, vtsp, aout);
  gemm8_kernel<0><<<dim3(512), dim3(512), 0, stream>>>(aout, wob, d_out);
}

// Round 5
// 307.978 us; speedup vs baseline: 1.6582x; 1.0161x over previous
//
#include <hip/hip_runtime.h>
#include <hip/hip_bf16.h>
#include <stdint.h>

#define NB 4
#define NT 8192
#define ND 1024
#define NH 16
#define NHD 64
#define NK 64        // top-k
#define NM (NB*NT)   // 32768

typedef __attribute__((ext_vector_type(4))) float f32x4;
typedef __attribute__((ext_vector_type(8))) short s16x8;
typedef const void __attribute__((address_space(1)))* gas1_t;
typedef void __attribute__((address_space(3)))* las3_t;

__device__ __forceinline__ float bf2f(ushort u) {
  union { uint32_t i; float f; } v; v.i = ((uint32_t)u) << 16; return v.f;
}
__device__ __forceinline__ ushort f2bf(float f) {
  union { float f; uint32_t i; } v; v.f = f;
  uint32_t r = v.i + 0x7FFFu + ((v.i >> 16) & 1u);
  return (ushort)(r >> 16);
}
__device__ __forceinline__ uint32_t f2ord(uint32_t u) {
  return (u & 0x80000000u) ? ~u : (u | 0x80000000u);
}

// ---- convert the four weight matrices to bf16 ----
__global__ __launch_bounds__(256) void convert_w_kernel(
    const float* __restrict__ Wq, const float* __restrict__ Wk,
    const float* __restrict__ Wv, const float* __restrict__ Wo,
    ushort* __restrict__ wqb, ushort* __restrict__ wkb,
    ushort* __restrict__ wvb, ushort* __restrict__ wob) {
  int i = blockIdx.x * 256 + threadIdx.x;   // grid covers exactly 1M
  wqb[i] = f2bf(Wq[i]); wkb[i] = f2bf(Wk[i]);
  wvb[i] = f2bf(Wv[i]); wob[i] = f2bf(Wo[i]);
}

// ---- u[h][e] = sum_d wscore[d] * Wk[h*64+d][e]  (fp32, exact path for topk) ----
__global__ __launch_bounds__(256) void prep_u_kernel(
    const float* __restrict__ Wk, const float* __restrict__ wscore,
    float* __restrict__ u) {
  int e = (blockIdx.x & 3) * 256 + threadIdx.x;
  int h = blockIdx.x >> 2;
  float acc = 0.f;
  #pragma unroll 8
  for (int d = 0; d < NHD; ++d) acc += wscore[d] * Wk[(size_t)(h*NHD + d)*ND + e];
  u[h*ND + e] = acc;
}

// ---- x -> bf16, and fp32 indexer scores[b*16+h][t] = x_row . u[h] ----
// u lives in VGPRs (lane owns u[0..15][its 4 elems]); packed butterfly reduce.
__global__ __launch_bounds__(256) void prep_x_kernel(
    const float* __restrict__ x, const float* __restrict__ u,
    ushort* __restrict__ xb, float* __restrict__ scores) {
  __shared__ float pbuf[16][4][17];   // [row-in-batch][wave][h], padded
  int t = threadIdx.x, w = t >> 6, l = t & 63;
  int e0 = w * 256 + l * 4;           // this lane's 4-elem slice of the row
  float4 uv[16];
  #pragma unroll
  for (int h = 0; h < 16; ++h) uv[h] = *(const float4*)(u + h * ND + e0);
  int row0 = blockIdx.x * 32;
  int boff = ((row0 >> 13) << 4);      // b*16
  int tt0 = row0 & (NT - 1);
  for (int batch = 0; batch < 2; ++batch) {   // 2 batches of 16 rows
    #pragma unroll 2
    for (int rr = 0; rr < 16; ++rr) {
      int row = row0 + batch * 16 + rr;
      float4 xv = *(const float4*)(x + (size_t)row * ND + e0);
      ushort4 o; o.x = f2bf(xv.x); o.y = f2bf(xv.y); o.z = f2bf(xv.z); o.w = f2bf(xv.w);
      *(ushort4*)(xb + (size_t)row * ND + e0) = o;
      float p[16];
      #pragma unroll
      for (int h = 0; h < 16; ++h)
        p[h] = xv.x*uv[h].x + xv.y*uv[h].y + xv.z*uv[h].z + xv.w*uv[h].w;
      float q8[8];
      #pragma unroll
      for (int j = 0; j < 8; ++j) {
        bool hi = (l & 1);
        float keep = hi ? p[2*j+1] : p[2*j];
        float send = hi ? p[2*j]   : p[2*j+1];
        q8[j] = keep + __shfl_xor(send, 1, 64);
      }
      float q4[4];
      #pragma unroll
      for (int j = 0; j < 4; ++j) {
        bool hi = ((l >> 1) & 1);
        float keep = hi ? q8[2*j+1] : q8[2*j];
        float send = hi ? q8[2*j]   : q8[2*j+1];
        q4[j] = keep + __shfl_xor(send, 2, 64);
      }
      float q2[2];
      #pragma unroll
      for (int j = 0; j < 2; ++j) {
        bool hi = ((l >> 2) & 1);
        float keep = hi ? q4[2*j+1] : q4[2*j];
        float send = hi ? q4[2*j]   : q4[2*j+1];
        q2[j] = keep + __shfl_xor(send, 4, 64);
      }
      float q1;
      {
        bool hi = ((l >> 3) & 1);
        float keep = hi ? q2[1] : q2[0];
        float send = hi ? q2[0] : q2[1];
        q1 = keep + __shfl_xor(send, 8, 64);
      }
      q1 += __shfl_xor(q1, 16, 64);
      q1 += __shfl_xor(q1, 32, 64);
      if (l < 16) pbuf[rr][w][l] = q1;   // h = l&15
    }
    __syncthreads();
    {
      int r16 = t & 15, h = t >> 4;      // consecutive t -> consecutive tt (coalesced)
      float s = pbuf[r16][0][h] + pbuf[r16][1][h] + pbuf[r16][2][h] + pbuf[r16][3][h];
      scores[(size_t)(boff + h) * NT + tt0 + batch * 16 + r16] = s;
    }
    __syncthreads();
  }
}

// ---- top-64 per (b,h) via single-pass radix-select (12-bit histogram) ----
__global__ __launch_bounds__(256) void topk_kernel(
    const float* __restrict__ scores, int* __restrict__ tidx) {
  int bh = blockIdx.x, t = threadIdx.x;
  __shared__ uint32_t keys[NT];      // 32 KiB order-preserving keys
  __shared__ int hist[4096];         // 16 KiB
  __shared__ uint32_t ck[512];
  __shared__ int ci[512];
  __shared__ int chunksum[256];
  __shared__ int s_binB, s_c0;
  __shared__ int cnt_hi, cnt_cand;

  for (int i = t; i < 4096; i += 256) hist[i] = 0;
  if (t == 0) { cnt_hi = 0; cnt_cand = 0; }
  __syncthreads();
  const uint4* sg = (const uint4*)(scores + (size_t)bh * NT);
  for (int i = t; i < NT/4; i += 256) {
    uint4 v = sg[i];
    uint32_t k0 = f2ord(v.x), k1 = f2ord(v.y), k2 = f2ord(v.z), k3 = f2ord(v.w);
    keys[i*4+0] = k0; keys[i*4+1] = k1; keys[i*4+2] = k2; keys[i*4+3] = k3;
    atomicAdd(&hist[k0 >> 20], 1); atomicAdd(&hist[k1 >> 20], 1);
    atomicAdd(&hist[k2 >> 20], 1); atomicAdd(&hist[k3 >> 20], 1);
  }
  __syncthreads();
  {
    int hi = 4095 - t * 16;
    int s = 0;
    #pragma unroll
    for (int j = 0; j < 16; ++j) s += hist[hi - j];
    chunksum[t] = s;
  }
  __syncthreads();
  if (t == 0) {
    int cum = 0, c = 0;
    while (cum + chunksum[c] < NK) { cum += chunksum[c]; ++c; }
    int bin = 4095 - c * 16;
    while (cum + hist[bin] < NK) { cum += hist[bin]; --bin; }
    s_binB = bin; s_c0 = cum;
  }
  __syncthreads();
  int binB = s_binB, c0 = s_c0;
  for (int i = t; i < NT; i += 256) {
    int b = keys[i] >> 20;
    if (b > binB) {
      int p = atomicAdd(&cnt_hi, 1);
      tidx[bh*NK + p] = i;
    } else if (b == binB) {
      int p = atomicAdd(&cnt_cand, 1);
      if (p < 512) { ck[p] = keys[i]; ci[p] = i; }
    }
  }
  __syncthreads();
  int nc = cnt_cand; if (nc > 512) nc = 512;
  int need = NK - c0;
  for (int p = t; p < nc; p += 256) {
    uint32_t myk = ck[p]; int myi = ci[p];
    int rank = 0;
    for (int j = 0; j < nc; ++j) {
      uint32_t kj = ck[j];
      rank += (kj > myk || (kj == myk && ci[j] < myi)) ? 1 : 0;
    }
    if (rank < need) tidx[bh*NK + c0 + rank] = myi;
  }
}

// ---- project ONLY the 64 selected rows per (b,h) into K_sp[key][d], V^T_sp[d][key] ----
__global__ __launch_bounds__(256) void sparse_kv_kernel(
    const ushort* __restrict__ xb, const ushort* __restrict__ wkb,
    const ushort* __restrict__ wvb, const int* __restrict__ tidx,
    ushort* __restrict__ ksp, ushort* __restrict__ vtsp) {
  int bh = blockIdx.x, gy = blockIdx.y;
  int b = bh >> 4, h = bh & 15;
  int t = threadIdx.x;
  __shared__ __align__(16) ushort xl[16][128];
  __shared__ int kid[16];
  if (t < 16) kid[t] = tidx[bh*NK + gy*16 + t];
  int d = t & 63, kq = t >> 6;
  float ak[4] = {0.f,0.f,0.f,0.f}, av[4] = {0.f,0.f,0.f,0.f};
  const ushort* wkr = wkb + (size_t)(h*NHD + d) * ND;
  const ushort* wvr = wvb + (size_t)(h*NHD + d) * ND;
  for (int kc = 0; kc < ND; kc += 128) {
    __syncthreads();
    {
      int row = t >> 4, c8 = (t & 15) * 8;
      *(uint4*)&xl[row][c8] = *(const uint4*)(xb + (size_t)(b*NT + kid[row]) * ND + kc + c8);
    }
    __syncthreads();
    #pragma unroll 1
    for (int sub = 0; sub < 8; ++sub) {
      s16x8 k0 = *(const s16x8*)(wkr + kc + sub*16);
      s16x8 k1 = *(const s16x8*)(wkr + kc + sub*16 + 8);
      s16x8 v0 = *(const s16x8*)(wvr + kc + sub*16);
      s16x8 v1 = *(const s16x8*)(wvr + kc + sub*16 + 8);
      float kf[16], vf2[16];
      #pragma unroll
      for (int j = 0; j < 8; ++j) {
        kf[j]  = bf2f((ushort)k0[j]); kf[8+j]  = bf2f((ushort)k1[j]);
        vf2[j] = bf2f((ushort)v0[j]); vf2[8+j] = bf2f((ushort)v1[j]);
      }
      #pragma unroll
      for (int kk = 0; kk < 4; ++kk) {
        #pragma unroll
        for (int j = 0; j < 16; ++j) {
          float xvv = bf2f(xl[kq*4 + kk][sub*16 + j]);
          ak[kk] += xvv * kf[j];
          av[kk] += xvv * vf2[j];
        }
      }
    }
  }
  #pragma unroll
  for (int kk = 0; kk < 4; ++kk) {
    int key = gy*16 + kq*4 + kk;
    ksp[((size_t)bh*NK + key)*NHD + d] = f2bf(ak[kk]);
    vtsp[((size_t)bh*NHD + d)*NK + key] = f2bf(av[kk]);
  }
}

// ==== 256x256 GEMM, 8 kh-split phases/K-tile: C[M,N]=A[M,K]@Bw[N,K]^T ====
// M=32768, N=K=1024. BM=BN=256, BK=64, 8 waves (2Mx4N), 128KiB LDS dbuf.
// Each phase: 8 MFMA on frag half-set [kh] while ds-reads prefetch into the
// DISJOINT half-set [kh^1] -> reads overlap MFMA issue within the phase.
// One s_barrier per phase; counted vmcnt(4) once per tile (never 0 mid-loop).
// Quadrant order (0,0),(0,1),(1,1),(1,0); B0 re-read at ph6/7 keeps single
// bfr set. Ledger: every STG-overwrite is >=2 barriers after its region's
// last reader; vmcnt(4)@ph8 exactly drains B0(kt+1) (kt=14 -> vmcnt(0)).
template<int STORE_BF16>
__global__ __launch_bounds__(512, 2) void gemm8_kernel(
    const ushort* __restrict__ A, const ushort* __restrict__ Bw,
    void* __restrict__ Cout) {
  __shared__ __align__(16) char lds[131072];
  const int t = threadIdx.x, wid = t >> 6, l = t & 63;
  const int wr = wid >> 2, wc = wid & 3;
  int bid = blockIdx.x;                  // nwg = 512 = 8 XCD * 64
  int wg = (bid & 7) * 64 + (bid >> 3);  // XCD swizzle (bijective, 512%8==0)
  int tm = wg >> 2, tn = wg & 3;
  const int K = 1024, N = 1024;
  const ushort* Ab = A + (size_t)tm * 256 * K;
  const ushort* Bb = Bw + (size_t)tn * 256 * K;
  // staging: lane covers row (l>>2) of its wave's 16-row stripe, 8 k-elems
  const int skh  = ((l & 3) * 8) ^ (((l >> 5) & 1) << 4);  // pre-swizzled src k
  const int srow = l >> 2;
  // ds_read: lane reads frag row base+(l&15), logical kh=(l>>4)*8, swizzled
  const int lane_off = (l & 15) * 64 + ((((l >> 4) * 8) ^ (((l >> 3) & 1) << 4)) * 2);
  f32x4 acc[8][4];
  #pragma unroll
  for (int i = 0; i < 8; ++i)
    #pragma unroll
    for (int j = 0; j < 4; ++j) acc[i][j] = (f32x4){0.f, 0.f, 0.f, 0.f};
  s16x8 afr[4][2], bfr[2][2];

#define STG(gbase, matoff, half, ktile, buf) do { \
    const ushort* _s = (gbase) + (size_t)((half)*128 + wid*16 + srow) * K + (ktile)*64 + skh; \
    int _d = (buf)*65536 + (matoff) + ((half)*128 + wid*16)*64; \
    __builtin_amdgcn_global_load_lds((gas1_t)_s, (las3_t)(lds + _d), 16, 0, 0); \
    __builtin_amdgcn_global_load_lds((gas1_t)(_s + 32), (las3_t)(lds + _d + 16384), 16, 0, 0); \
  } while (0)

#define RD_A(mh, kh, buf) do { \
    _Pragma("unroll") \
    for (int mi = 0; mi < 4; ++mi) \
      afr[mi][kh] = *(const s16x8*)(lds + (buf)*65536 + (kh)*16384 + \
                      ((((mh)*2 + wr)*64 + mi*16))*64 + lane_off); \
  } while (0)

#define RD_B(nh, kh, buf) do { \
    _Pragma("unroll") \
    for (int ni = 0; ni < 2; ++ni) \
      bfr[ni][kh] = *(const s16x8*)(lds + (buf)*65536 + 32768 + (kh)*16384 + \
                      (((nh)*128 + wc*32 + ni*16))*64 + lane_off); \
  } while (0)

#define MMAQH(mh, nh, kh) do { \
    __builtin_amdgcn_s_setprio(1); \
    _Pragma("unroll") \
    for (int mi = 0; mi < 4; ++mi) \
      _Pragma("unroll") \
      for (int ni = 0; ni < 2; ++ni) \
        acc[(mh)*4+mi][(nh)*2+ni] = __builtin_amdgcn_mfma_f32_16x16x32_bf16( \
            afr[mi][kh], bfr[ni][kh], acc[(mh)*4+mi][(nh)*2+ni], 0, 0, 0); \
    __builtin_amdgcn_s_setprio(0); \
  } while (0)

#define LG0() do { asm volatile("s_waitcnt lgkmcnt(0)" ::: "memory"); \
                   __builtin_amdgcn_sched_barrier(0); } while (0)
#define ENDPH() do { __builtin_amdgcn_sched_barrier(0); \
                     __builtin_amdgcn_s_barrier(); } while (0)

#define TILE(kt, bc, bn) do { \
  /* ph1 (0,0)k0 ; prefetch A0k1,B0k1 */ \
  LG0(); MMAQH(0,0,0); RD_A(0,1,bc); RD_B(0,1,bc); ENDPH(); \
  /* ph2 (0,0)k1 ; prefetch B1k0 ; stage B0(kt+1) */ \
  LG0(); MMAQH(0,0,1); RD_B(1,0,bc); \
  if ((kt)+1 < 16) STG(Bb,32768,0,(kt)+1,bn); ENDPH(); \
  /* ph3 (0,1)k0 ; prefetch B1k1 */ \
  LG0(); MMAQH(0,1,0); RD_B(1,1,bc); ENDPH(); \
  /* ph4 (0,1)k1 ; prefetch A1k0 ; stage A0(kt+2) */ \
  LG0(); MMAQH(0,1,1); RD_A(1,0,bc); \
  if ((kt)+2 < 16) STG(Ab,0,0,(kt)+2,bc); ENDPH(); \
  /* ph5 (1,1)k0 ; prefetch A1k1 */ \
  LG0(); MMAQH(1,1,0); RD_A(1,1,bc); ENDPH(); \
  /* ph6 (1,1)k1 ; prefetch B0k0 (re-read) ; stage B1(kt+2) */ \
  LG0(); MMAQH(1,1,1); RD_B(0,0,bc); \
  if ((kt)+2 < 16) STG(Bb,32768,1,(kt)+2,bc); ENDPH(); \
  /* ph7 (1,0)k0 ; prefetch B0k1 (re-read) */ \
  LG0(); MMAQH(1,0,0); RD_B(0,1,bc); ENDPH(); \
  /* ph8 (1,0)k1 ; vmcnt-verify kt+1 ; boundary reads + stage A1(kt+2) */ \
  LG0(); MMAQH(1,0,1); \
  if ((kt) < 14)       { asm volatile("s_waitcnt vmcnt(4)" ::: "memory"); } \
  else if ((kt) == 14) { asm volatile("s_waitcnt vmcnt(0)" ::: "memory"); } \
  __builtin_amdgcn_sched_barrier(0); \
  __builtin_amdgcn_s_barrier(); \
  if ((kt)+1 < 16) { RD_A(0,0,bn); RD_B(0,0,bn); } \
  if ((kt)+2 < 16) STG(Ab,0,1,(kt)+2,bc); \
} while (0)

  // prologue: t0 all 4 halves + t1 {A0,B1,A1}; B0(t1) arrives at ph2 of t0
  STG(Ab,0,0,0,0); STG(Bb,32768,0,0,0); STG(Ab,0,1,0,0); STG(Bb,32768,1,0,0);
  STG(Ab,0,0,1,1); STG(Bb,32768,1,1,1); STG(Ab,0,1,1,1);
  asm volatile("s_waitcnt vmcnt(6)" ::: "memory");   // t0's 8 loads done
  __builtin_amdgcn_s_barrier();
  RD_A(0,0,0); RD_B(0,0,0);                          // A0k0,B0k0 of t0

  for (int k2 = 0; k2 < 8; ++k2) {
    TILE(2*k2,     0, 1);
    TILE(2*k2 + 1, 1, 0);
  }
#undef TILE
#undef STG
#undef RD_A
#undef RD_B
#undef MMAQH
#undef LG0
#undef ENDPH

  // epilogue: C/D layout col=l&15, row=(l>>4)*4+r
  #pragma unroll
  for (int mi8 = 0; mi8 < 8; ++mi8) {
    int grow = tm*256 + (((mi8 >> 2)*2 + wr)*64) + (mi8 & 3)*16 + (l >> 4)*4;
    #pragma unroll
    for (int ni4 = 0; ni4 < 4; ++ni4) {
      int gcol = tn*256 + (ni4 >> 1)*128 + wc*32 + (ni4 & 1)*16 + (l & 15);
      #pragma unroll
      for (int r = 0; r < 4; ++r) {
        size_t off = (size_t)(grow + r) * N + gcol;
        if (STORE_BF16) ((ushort*)Cout)[off] = f2bf(acc[mi8][ni4][r]);
        else            ((float*)Cout)[off]  = acc[mi8][ni4][r];
      }
    }
  }
}

// ---- attention vs 64 keys: per-wave 64 q-rows; K/V frags live in registers ----
__global__ __launch_bounds__(256) void attn_kernel(
    const ushort* __restrict__ qg, const ushort* __restrict__ ksp,
    const ushort* __restrict__ vtsp, ushort* __restrict__ aout) {
  int bh = blockIdx.y;
  int b = bh >> 4, h = bh & 15;
  int t = threadIdx.x, w = t >> 6, l = t & 63;
  __shared__ __align__(16) ushort Pl[4][1024];
  const ushort* kb = ksp + (size_t)bh * NK * NHD;
  const ushort* vb = vtsp + (size_t)bh * NHD * NK;
  s16x8 kf[2][4], vf[2][4];
  #pragma unroll
  for (int ks = 0; ks < 2; ++ks)
    #pragma unroll
    for (int ni = 0; ni < 4; ++ni) {
      kf[ks][ni] = *(const s16x8*)&kb[(size_t)(ni*16 + (l & 15))*NHD + ks*32 + (l >> 4)*8];
      vf[ks][ni] = *(const s16x8*)&vb[(size_t)(ni*16 + (l & 15))*NK + ks*32 + (l >> 4)*8];
    }
  int rowbase = blockIdx.x * 256 + w * 64;
  #pragma unroll 1
  for (int mi = 0; mi < 4; ++mi) {
    int r0 = rowbase + mi * 16;
    s16x8 af[2];
    #pragma unroll
    for (int ks = 0; ks < 2; ++ks)
      af[ks] = *(const s16x8*)&qg[(size_t)(b*NT + r0 + (l & 15))*ND + h*NHD + ks*32 + (l >> 4)*8];
    f32x4 sc[4];
    #pragma unroll
    for (int ni = 0; ni < 4; ++ni) {
      f32x4 z; z[0]=0.f; z[1]=0.f; z[2]=0.f; z[3]=0.f;
      z = __builtin_amdgcn_mfma_f32_16x16x32_bf16(af[0], kf[0][ni], z, 0, 0, 0);
      sc[ni] = __builtin_amdgcn_mfma_f32_16x16x32_bf16(af[1], kf[1][ni], z, 0, 0, 0);
    }
    #pragma unroll
    for (int r = 0; r < 4; ++r) {
      float v0 = sc[0][r]*0.125f, v1 = sc[1][r]*0.125f;
      float v2 = sc[2][r]*0.125f, v3 = sc[3][r]*0.125f;
      float m = fmaxf(fmaxf(v0, v1), fmaxf(v2, v3));
      #pragma unroll
      for (int mm = 8; mm >= 1; mm >>= 1) m = fmaxf(m, __shfl_xor(m, mm, 64));
      float e0 = __expf(v0 - m), e1 = __expf(v1 - m);
      float e2 = __expf(v2 - m), e3 = __expf(v3 - m);
      float s = e0 + e1 + e2 + e3;
      #pragma unroll
      for (int mm = 8; mm >= 1; mm >>= 1) s += __shfl_xor(s, mm, 64);
      float inv = 1.f / s;
      int prow = (l >> 4)*4 + r;
      int lo = l & 7, hb = (l >> 3) & 1, sw = prow & 7;
      Pl[w][prow*64 + ((0 + hb) ^ sw)*8 + lo] = f2bf(e0 * inv);
      Pl[w][prow*64 + ((2 + hb) ^ sw)*8 + lo] = f2bf(e1 * inv);
      Pl[w][prow*64 + ((4 + hb) ^ sw)*8 + lo] = f2bf(e2 * inv);
      Pl[w][prow*64 + ((6 + hb) ^ sw)*8 + lo] = f2bf(e3 * inv);
    }
    s16x8 pf[2];
    #pragma unroll
    for (int ks = 0; ks < 2; ++ks)
      pf[ks] = *(const s16x8*)&Pl[w][(l & 15)*64 + ((ks*4 + (l >> 4)) ^ (l & 7))*8];
    f32x4 oc[4];
    #pragma unroll
    for (int ni = 0; ni < 4; ++ni) {
      f32x4 z; z[0]=0.f; z[1]=0.f; z[2]=0.f; z[3]=0.f;
      z = __builtin_amdgcn_mfma_f32_16x16x32_bf16(pf[0], vf[0][ni], z, 0, 0, 0);
      oc[ni] = __builtin_amdgcn_mfma_f32_16x16x32_bf16(pf[1], vf[1][ni], z, 0, 0, 0);
    }
    #pragma unroll
    for (int ni = 0; ni < 4; ++ni)
      #pragma unroll
      for (int r = 0; r < 4; ++r) {
        int row = r0 + (l >> 4)*4 + r;
        aout[(size_t)(b*NT + row)*ND + h*NHD + ni*16 + (l & 15)] = f2bf(oc[ni][r]);
      }
  }
}

extern "C" void kernel_launch(void* const* d_in, const int* in_sizes, int n_in,
                              void* d_out, int out_size, void* d_ws, size_t ws_size,
                              hipStream_t stream) {
  (void)in_sizes; (void)n_in; (void)out_size; (void)ws_size;
  const float* x  = (const float*)d_in[0];
  const float* Wq = (const float*)d_in[1];
  const float* Wk = (const float*)d_in[2];
  const float* Wv = (const float*)d_in[3];
  const float* Wo = (const float*)d_in[4];
  const float* wscore = (const float*)d_in[5];

  char* base = (char*)d_ws;
  ushort* xb     = (ushort*)(base + 0);           // 64 MiB  (reused as attn out)
  ushort* qb     = (ushort*)(base + 67108864);    // 64 MiB
  float*  scores = (float*) (base + 134217728);   // 2 MiB
  float*  u      = (float*) (base + 136314880);   // 64 KiB
  ushort* wqb    = (ushort*)(base + 136380416);   // 2 MiB
  ushort* wkb    = (ushort*)(base + 138477568);   // 2 MiB
  ushort* wvb    = (ushort*)(base + 140574720);   // 2 MiB
  ushort* wob    = (ushort*)(base + 142671872);   // 2 MiB
  int*    tidx   = (int*)   (base + 144769024);   // 16 KiB
  ushort* ksp    = (ushort*)(base + 144785408);   // 512 KiB
  ushort* vtsp   = (ushort*)(base + 145309696);   // 512 KiB
  ushort* aout   = xb;   // xb is dead after gemm_q + sparse_kv

  convert_w_kernel<<<dim3(4096), dim3(256), 0, stream>>>(Wq, Wk, Wv, Wo, wqb, wkb, wvb, wob);
  prep_u_kernel<<<dim3(64), dim3(256), 0, stream>>>(Wk, wscore, u);
  prep_x_kernel<<<dim3(1024), dim3(256), 0, stream>>>(x, u, xb, scores);
  topk_kernel<<<dim3(64), dim3(256), 0, stream>>>(scores, tidx);
  sparse_kv_kernel<<<dim3(64, 4), dim3(256), 0, stream>>>(xb, wkb, wvb, tidx, ksp, vtsp);
  gemm8_kernel<1><<<dim3(512), dim3(512), 0, stream>>>(xb, wqb, (void*)qb);
  attn_kernel<<<dim3(32, 64), dim3(256), 0, stream>>>(qb, ksp, vtsp, aout);
  gemm8_kernel<0><<<dim3(512), dim3(512), 0, stream>>>(aout, wob, d_out);
}

// Round 6
// 295.539 us; speedup vs baseline: 1.7280x; 1.0421x over previous
//
#include <hip/hip_runtime.h>
#include <hip/hip_bf16.h>
#include <stdint.h>

#define NB 4
#define NT 8192
#define ND 1024
#define NH 16
#define NHD 64
#define NK 64        // top-k
#define NM (NB*NT)   // 32768

typedef __attribute__((ext_vector_type(4))) float f32x4;
typedef __attribute__((ext_vector_type(8))) short s16x8;
typedef const void __attribute__((address_space(1)))* gas1_t;
typedef void __attribute__((address_space(3)))* las3_t;

__device__ __forceinline__ float bf2f(ushort u) {
  union { uint32_t i; float f; } v; v.i = ((uint32_t)u) << 16; return v.f;
}
__device__ __forceinline__ ushort f2bf(float f) {
  union { float f; uint32_t i; } v; v.f = f;
  uint32_t r = v.i + 0x7FFFu + ((v.i >> 16) & 1u);
  return (ushort)(r >> 16);
}
__device__ __forceinline__ uint32_t f2ord(uint32_t u) {
  return (u & 0x80000000u) ? ~u : (u | 0x80000000u);
}

// ---- convert the four weight matrices to bf16 ----
__global__ __launch_bounds__(256) void convert_w_kernel(
    const float* __restrict__ Wq, const float* __restrict__ Wk,
    const float* __restrict__ Wv, const float* __restrict__ Wo,
    ushort* __restrict__ wqb, ushort* __restrict__ wkb,
    ushort* __restrict__ wvb, ushort* __restrict__ wob) {
  int i = blockIdx.x * 256 + threadIdx.x;   // grid covers exactly 1M
  wqb[i] = f2bf(Wq[i]); wkb[i] = f2bf(Wk[i]);
  wvb[i] = f2bf(Wv[i]); wob[i] = f2bf(Wo[i]);
}

// ---- u[h][e] = sum_d wscore[d] * Wk[h*64+d][e]  (fp32, exact path for topk) ----
__global__ __launch_bounds__(256) void prep_u_kernel(
    const float* __restrict__ Wk, const float* __restrict__ wscore,
    float* __restrict__ u) {
  int e = (blockIdx.x & 3) * 256 + threadIdx.x;
  int h = blockIdx.x >> 2;
  float acc = 0.f;
  #pragma unroll 8
  for (int d = 0; d < NHD; ++d) acc += wscore[d] * Wk[(size_t)(h*NHD + d)*ND + e];
  u[h*ND + e] = acc;
}

// ---- x -> bf16, and fp32 indexer scores[b*16+h][t] = x_row . u[h] ----
// u lives in VGPRs (lane owns u[0..15][its 4 elems]); packed butterfly reduce.
// launch_bounds(256,4): 128-VGPR cap so uv[16] (64 VGPRs) stays RESIDENT —
// the default 8-waves/EU target capped at 64 VGPR and spilled uv (R5: VGPR=52).
__global__ __launch_bounds__(256, 4) void prep_x_kernel(
    const float* __restrict__ x, const float* __restrict__ u,
    ushort* __restrict__ xb, float* __restrict__ scores) {
  __shared__ float pbuf[16][4][17];   // [row-in-batch][wave][h], padded
  int t = threadIdx.x, w = t >> 6, l = t & 63;
  int e0 = w * 256 + l * 4;           // this lane's 4-elem slice of the row
  float4 uv[16];
  #pragma unroll
  for (int h = 0; h < 16; ++h) uv[h] = *(const float4*)(u + h * ND + e0);
  int row0 = blockIdx.x * 32;
  int boff = ((row0 >> 13) << 4);      // b*16
  int tt0 = row0 & (NT - 1);
  for (int batch = 0; batch < 2; ++batch) {   // 2 batches of 16 rows
    #pragma unroll 2
    for (int rr = 0; rr < 16; ++rr) {
      int row = row0 + batch * 16 + rr;
      float4 xv = *(const float4*)(x + (size_t)row * ND + e0);
      ushort4 o; o.x = f2bf(xv.x); o.y = f2bf(xv.y); o.z = f2bf(xv.z); o.w = f2bf(xv.w);
      *(ushort4*)(xb + (size_t)row * ND + e0) = o;
      float p[16];
      #pragma unroll
      for (int h = 0; h < 16; ++h)
        p[h] = xv.x*uv[h].x + xv.y*uv[h].y + xv.z*uv[h].z + xv.w*uv[h].w;
      float q8[8];
      #pragma unroll
      for (int j = 0; j < 8; ++j) {
        bool hi = (l & 1);
        float keep = hi ? p[2*j+1] : p[2*j];
        float send = hi ? p[2*j]   : p[2*j+1];
        q8[j] = keep + __shfl_xor(send, 1, 64);
      }
      float q4[4];
      #pragma unroll
      for (int j = 0; j < 4; ++j) {
        bool hi = ((l >> 1) & 1);
        float keep = hi ? q8[2*j+1] : q8[2*j];
        float send = hi ? q8[2*j]   : q8[2*j+1];
        q4[j] = keep + __shfl_xor(send, 2, 64);
      }
      float q2[2];
      #pragma unroll
      for (int j = 0; j < 2; ++j) {
        bool hi = ((l >> 2) & 1);
        float keep = hi ? q4[2*j+1] : q4[2*j];
        float send = hi ? q4[2*j]   : q4[2*j+1];
        q2[j] = keep + __shfl_xor(send, 4, 64);
      }
      float q1;
      {
        bool hi = ((l >> 3) & 1);
        float keep = hi ? q2[1] : q2[0];
        float send = hi ? q2[0] : q2[1];
        q1 = keep + __shfl_xor(send, 8, 64);
      }
      q1 += __shfl_xor(q1, 16, 64);
      q1 += __shfl_xor(q1, 32, 64);
      if (l < 16) pbuf[rr][w][l] = q1;   // h = l&15
    }
    __syncthreads();
    {
      int r16 = t & 15, h = t >> 4;      // consecutive t -> consecutive tt (coalesced)
      float s = pbuf[r16][0][h] + pbuf[r16][1][h] + pbuf[r16][2][h] + pbuf[r16][3][h];
      scores[(size_t)(boff + h) * NT + tt0 + batch * 16 + r16] = s;
    }
    __syncthreads();
  }
}

// ---- top-64 per (b,h) via single-pass radix-select (12-bit histogram) ----
__global__ __launch_bounds__(256) void topk_kernel(
    const float* __restrict__ scores, int* __restrict__ tidx) {
  int bh = blockIdx.x, t = threadIdx.x;
  __shared__ uint32_t keys[NT];      // 32 KiB order-preserving keys
  __shared__ int hist[4096];         // 16 KiB
  __shared__ uint32_t ck[512];
  __shared__ int ci[512];
  __shared__ int chunksum[256];
  __shared__ int s_binB, s_c0;
  __shared__ int cnt_hi, cnt_cand;

  for (int i = t; i < 4096; i += 256) hist[i] = 0;
  if (t == 0) { cnt_hi = 0; cnt_cand = 0; }
  __syncthreads();
  const uint4* sg = (const uint4*)(scores + (size_t)bh * NT);
  for (int i = t; i < NT/4; i += 256) {
    uint4 v = sg[i];
    uint32_t k0 = f2ord(v.x), k1 = f2ord(v.y), k2 = f2ord(v.z), k3 = f2ord(v.w);
    keys[i*4+0] = k0; keys[i*4+1] = k1; keys[i*4+2] = k2; keys[i*4+3] = k3;
    atomicAdd(&hist[k0 >> 20], 1); atomicAdd(&hist[k1 >> 20], 1);
    atomicAdd(&hist[k2 >> 20], 1); atomicAdd(&hist[k3 >> 20], 1);
  }
  __syncthreads();
  {
    int hi = 4095 - t * 16;
    int s = 0;
    #pragma unroll
    for (int j = 0; j < 16; ++j) s += hist[hi - j];
    chunksum[t] = s;
  }
  __syncthreads();
  if (t == 0) {
    int cum = 0, c = 0;
    while (cum + chunksum[c] < NK) { cum += chunksum[c]; ++c; }
    int bin = 4095 - c * 16;
    while (cum + hist[bin] < NK) { cum += hist[bin]; --bin; }
    s_binB = bin; s_c0 = cum;
  }
  __syncthreads();
  int binB = s_binB, c0 = s_c0;
  for (int i = t; i < NT; i += 256) {
    int b = keys[i] >> 20;
    if (b > binB) {
      int p = atomicAdd(&cnt_hi, 1);
      tidx[bh*NK + p] = i;
    } else if (b == binB) {
      int p = atomicAdd(&cnt_cand, 1);
      if (p < 512) { ck[p] = keys[i]; ci[p] = i; }
    }
  }
  __syncthreads();
  int nc = cnt_cand; if (nc > 512) nc = 512;
  int need = NK - c0;
  for (int p = t; p < nc; p += 256) {
    uint32_t myk = ck[p]; int myi = ci[p];
    int rank = 0;
    for (int j = 0; j < nc; ++j) {
      uint32_t kj = ck[j];
      rank += (kj > myk || (kj == myk && ci[j] < myi)) ? 1 : 0;
    }
    if (rank < need) tidx[bh*NK + c0 + rank] = myi;
  }
}

// ---- project ONLY the 64 selected rows per (b,h) into K_sp[key][d], V^T_sp[d][key] ----
__global__ __launch_bounds__(256, 4) void sparse_kv_kernel(
    const ushort* __restrict__ xb, const ushort* __restrict__ wkb,
    const ushort* __restrict__ wvb, const int* __restrict__ tidx,
    ushort* __restrict__ ksp, ushort* __restrict__ vtsp) {
  int bh = blockIdx.x, gy = blockIdx.y;
  int b = bh >> 4, h = bh & 15;
  int t = threadIdx.x;
  __shared__ __align__(16) ushort xl[16][128];
  __shared__ int kid[16];
  if (t < 16) kid[t] = tidx[bh*NK + gy*16 + t];
  int d = t & 63, kq = t >> 6;
  float ak[4] = {0.f,0.f,0.f,0.f}, av[4] = {0.f,0.f,0.f,0.f};
  const ushort* wkr = wkb + (size_t)(h*NHD + d) * ND;
  const ushort* wvr = wvb + (size_t)(h*NHD + d) * ND;
  for (int kc = 0; kc < ND; kc += 128) {
    __syncthreads();
    {
      int row = t >> 4, c8 = (t & 15) * 8;
      *(uint4*)&xl[row][c8] = *(const uint4*)(xb + (size_t)(b*NT + kid[row]) * ND + kc + c8);
    }
    __syncthreads();
    #pragma unroll 1
    for (int sub = 0; sub < 8; ++sub) {
      s16x8 k0 = *(const s16x8*)(wkr + kc + sub*16);
      s16x8 k1 = *(const s16x8*)(wkr + kc + sub*16 + 8);
      s16x8 v0 = *(const s16x8*)(wvr + kc + sub*16);
      s16x8 v1 = *(const s16x8*)(wvr + kc + sub*16 + 8);
      float kf[16], vf2[16];
      #pragma unroll
      for (int j = 0; j < 8; ++j) {
        kf[j]  = bf2f((ushort)k0[j]); kf[8+j]  = bf2f((ushort)k1[j]);
        vf2[j] = bf2f((ushort)v0[j]); vf2[8+j] = bf2f((ushort)v1[j]);
      }
      #pragma unroll
      for (int kk = 0; kk < 4; ++kk) {
        #pragma unroll
        for (int j = 0; j < 16; ++j) {
          float xvv = bf2f(xl[kq*4 + kk][sub*16 + j]);
          ak[kk] += xvv * kf[j];
          av[kk] += xvv * vf2[j];
        }
      }
    }
  }
  #pragma unroll
  for (int kk = 0; kk < 4; ++kk) {
    int key = gy*16 + kq*4 + kk;
    ksp[((size_t)bh*NK + key)*NHD + d] = f2bf(ak[kk]);
    vtsp[((size_t)bh*NHD + d)*NK + key] = f2bf(av[kk]);
  }
}

// ==== 256x256 GEMM, 8 kh-split phases/K-tile: C[M,N]=A[M,K]@Bw[N,K]^T ====
// M=32768, N=K=1024. BM=BN=256, BK=64, 8 waves (2Mx4N), 128KiB LDS dbuf.
// Each phase: 8 MFMA on frag half-set [kh] while ds-reads prefetch into the
// DISJOINT half-set [kh^1] -> reads overlap MFMA issue within the phase.
// One s_barrier per phase; counted vmcnt(4) once per tile (never 0 mid-loop).
template<int STORE_BF16>
__global__ __launch_bounds__(512, 2) void gemm8_kernel(
    const ushort* __restrict__ A, const ushort* __restrict__ Bw,
    void* __restrict__ Cout) {
  __shared__ __align__(16) char lds[131072];
  const int t = threadIdx.x, wid = t >> 6, l = t & 63;
  const int wr = wid >> 2, wc = wid & 3;
  int bid = blockIdx.x;                  // nwg = 512 = 8 XCD * 64
  int wg = (bid & 7) * 64 + (bid >> 3);  // XCD swizzle (bijective, 512%8==0)
  int tm = wg >> 2, tn = wg & 3;
  const int K = 1024, N = 1024;
  const ushort* Ab = A + (size_t)tm * 256 * K;
  const ushort* Bb = Bw + (size_t)tn * 256 * K;
  const int skh  = ((l & 3) * 8) ^ (((l >> 5) & 1) << 4);  // pre-swizzled src k
  const int srow = l >> 2;
  const int lane_off = (l & 15) * 64 + ((((l >> 4) * 8) ^ (((l >> 3) & 1) << 4)) * 2);
  f32x4 acc[8][4];
  #pragma unroll
  for (int i = 0; i < 8; ++i)
    #pragma unroll
    for (int j = 0; j < 4; ++j) acc[i][j] = (f32x4){0.f, 0.f, 0.f, 0.f};
  s16x8 afr[4][2], bfr[2][2];

#define STG(gbase, matoff, half, ktile, buf) do { \
    const ushort* _s = (gbase) + (size_t)((half)*128 + wid*16 + srow) * K + (ktile)*64 + skh; \
    int _d = (buf)*65536 + (matoff) + ((half)*128 + wid*16)*64; \
    __builtin_amdgcn_global_load_lds((gas1_t)_s, (las3_t)(lds + _d), 16, 0, 0); \
    __builtin_amdgcn_global_load_lds((gas1_t)(_s + 32), (las3_t)(lds + _d + 16384), 16, 0, 0); \
  } while (0)

#define RD_A(mh, kh, buf) do { \
    _Pragma("unroll") \
    for (int mi = 0; mi < 4; ++mi) \
      afr[mi][kh] = *(const s16x8*)(lds + (buf)*65536 + (kh)*16384 + \
                      ((((mh)*2 + wr)*64 + mi*16))*64 + lane_off); \
  } while (0)

#define RD_B(nh, kh, buf) do { \
    _Pragma("unroll") \
    for (int ni = 0; ni < 2; ++ni) \
      bfr[ni][kh] = *(const s16x8*)(lds + (buf)*65536 + 32768 + (kh)*16384 + \
                      (((nh)*128 + wc*32 + ni*16))*64 + lane_off); \
  } while (0)

#define MMAQH(mh, nh, kh) do { \
    __builtin_amdgcn_s_setprio(1); \
    _Pragma("unroll") \
    for (int mi = 0; mi < 4; ++mi) \
      _Pragma("unroll") \
      for (int ni = 0; ni < 2; ++ni) \
        acc[(mh)*4+mi][(nh)*2+ni] = __builtin_amdgcn_mfma_f32_16x16x32_bf16( \
            afr[mi][kh], bfr[ni][kh], acc[(mh)*4+mi][(nh)*2+ni], 0, 0, 0); \
    __builtin_amdgcn_s_setprio(0); \
  } while (0)

#define LG0() do { asm volatile("s_waitcnt lgkmcnt(0)" ::: "memory"); \
                   __builtin_amdgcn_sched_barrier(0); } while (0)
#define ENDPH() do { __builtin_amdgcn_sched_barrier(0); \
                     __builtin_amdgcn_s_barrier(); } while (0)

#define TILE(kt, bc, bn) do { \
  LG0(); MMAQH(0,0,0); RD_A(0,1,bc); RD_B(0,1,bc); ENDPH(); \
  LG0(); MMAQH(0,0,1); RD_B(1,0,bc); \
  if ((kt)+1 < 16) STG(Bb,32768,0,(kt)+1,bn); ENDPH(); \
  LG0(); MMAQH(0,1,0); RD_B(1,1,bc); ENDPH(); \
  LG0(); MMAQH(0,1,1); RD_A(1,0,bc); \
  if ((kt)+2 < 16) STG(Ab,0,0,(kt)+2,bc); ENDPH(); \
  LG0(); MMAQH(1,1,0); RD_A(1,1,bc); ENDPH(); \
  LG0(); MMAQH(1,1,1); RD_B(0,0,bc); \
  if ((kt)+2 < 16) STG(Bb,32768,1,(kt)+2,bc); ENDPH(); \
  LG0(); MMAQH(1,0,0); RD_B(0,1,bc); ENDPH(); \
  LG0(); MMAQH(1,0,1); \
  if ((kt) < 14)       { asm volatile("s_waitcnt vmcnt(4)" ::: "memory"); } \
  else if ((kt) == 14) { asm volatile("s_waitcnt vmcnt(0)" ::: "memory"); } \
  __builtin_amdgcn_sched_barrier(0); \
  __builtin_amdgcn_s_barrier(); \
  if ((kt)+1 < 16) { RD_A(0,0,bn); RD_B(0,0,bn); } \
  if ((kt)+2 < 16) STG(Ab,0,1,(kt)+2,bc); \
} while (0)

  // prologue: t0 all 4 halves + t1 {A0,B1,A1}; B0(t1) arrives at ph2 of t0
  STG(Ab,0,0,0,0); STG(Bb,32768,0,0,0); STG(Ab,0,1,0,0); STG(Bb,32768,1,0,0);
  STG(Ab,0,0,1,1); STG(Bb,32768,1,1,1); STG(Ab,0,1,1,1);
  asm volatile("s_waitcnt vmcnt(6)" ::: "memory");   // t0's 8 loads done
  __builtin_amdgcn_s_barrier();
  RD_A(0,0,0); RD_B(0,0,0);                          // A0k0,B0k0 of t0

  for (int k2 = 0; k2 < 8; ++k2) {
    TILE(2*k2,     0, 1);
    TILE(2*k2 + 1, 1, 0);
  }
#undef TILE
#undef STG
#undef RD_A
#undef RD_B
#undef MMAQH
#undef LG0
#undef ENDPH

  // epilogue: C/D layout col=l&15, row=(l>>4)*4+r
  #pragma unroll
  for (int mi8 = 0; mi8 < 8; ++mi8) {
    int grow = tm*256 + (((mi8 >> 2)*2 + wr)*64) + (mi8 & 3)*16 + (l >> 4)*4;
    #pragma unroll
    for (int ni4 = 0; ni4 < 4; ++ni4) {
      int gcol = tn*256 + (ni4 >> 1)*128 + wc*32 + (ni4 & 1)*16 + (l & 15);
      #pragma unroll
      for (int r = 0; r < 4; ++r) {
        size_t off = (size_t)(grow + r) * N + gcol;
        if (STORE_BF16) ((ushort*)Cout)[off] = f2bf(acc[mi8][ni4][r]);
        else            ((float*)Cout)[off]  = acc[mi8][ni4][r];
      }
    }
  }
}

// ---- attention vs 64 keys: per-wave 64 q-rows; K/V frags live in registers ----
// launch_bounds(256,2): 256-VGPR cap so kf/vf (64 VGPRs) stay resident.
__global__ __launch_bounds__(256, 2) void attn_kernel(
    const ushort* __restrict__ qg, const ushort* __restrict__ ksp,
    const ushort* __restrict__ vtsp, ushort* __restrict__ aout) {
  int bh = blockIdx.y;
  int b = bh >> 4, h = bh & 15;
  int t = threadIdx.x, w = t >> 6, l = t & 63;
  __shared__ __align__(16) ushort Pl[4][1024];
  const ushort* kb = ksp + (size_t)bh * NK * NHD;
  const ushort* vb = vtsp + (size_t)bh * NHD * NK;
  s16x8 kf[2][4], vf[2][4];
  #pragma unroll
  for (int ks = 0; ks < 2; ++ks)
    #pragma unroll
    for (int ni = 0; ni < 4; ++ni) {
      kf[ks][ni] = *(const s16x8*)&kb[(size_t)(ni*16 + (l & 15))*NHD + ks*32 + (l >> 4)*8];
      vf[ks][ni] = *(const s16x8*)&vb[(size_t)(ni*16 + (l & 15))*NK + ks*32 + (l >> 4)*8];
    }
  int rowbase = blockIdx.x * 256 + w * 64;
  #pragma unroll 1
  for (int mi = 0; mi < 4; ++mi) {
    int r0 = rowbase + mi * 16;
    s16x8 af[2];
    #pragma unroll
    for (int ks = 0; ks < 2; ++ks)
      af[ks] = *(const s16x8*)&qg[(size_t)(b*NT + r0 + (l & 15))*ND + h*NHD + ks*32 + (l >> 4)*8];
    f32x4 sc[4];
    #pragma unroll
    for (int ni = 0; ni < 4; ++ni) {
      f32x4 z; z[0]=0.f; z[1]=0.f; z[2]=0.f; z[3]=0.f;
      z = __builtin_amdgcn_mfma_f32_16x16x32_bf16(af[0], kf[0][ni], z, 0, 0, 0);
      sc[ni] = __builtin_amdgcn_mfma_f32_16x16x32_bf16(af[1], kf[1][ni], z, 0, 0, 0);
    }
    #pragma unroll
    for (int r = 0; r < 4; ++r) {
      float v0 = sc[0][r]*0.125f, v1 = sc[1][r]*0.125f;
      float v2 = sc[2][r]*0.125f, v3 = sc[3][r]*0.125f;
      float m = fmaxf(fmaxf(v0, v1), fmaxf(v2, v3));
      #pragma unroll
      for (int mm = 8; mm >= 1; mm >>= 1) m = fmaxf(m, __shfl_xor(m, mm, 64));
      float e0 = __expf(v0 - m), e1 = __expf(v1 - m);
      float e2 = __expf(v2 - m), e3 = __expf(v3 - m);
      float s = e0 + e1 + e2 + e3;
      #pragma unroll
      for (int mm = 8; mm >= 1; mm >>= 1) s += __shfl_xor(s, mm, 64);
      float inv = 1.f / s;
      int prow = (l >> 4)*4 + r;
      int lo = l & 7, hb = (l >> 3) & 1, sw = prow & 7;
      Pl[w][prow*64 + ((0 + hb) ^ sw)*8 + lo] = f2bf(e0 * inv);
      Pl[w][prow*64 + ((2 + hb) ^ sw)*8 + lo] = f2bf(e1 * inv);
      Pl[w][prow*64 + ((4 + hb) ^ sw)*8 + lo] = f2bf(e2 * inv);
      Pl[w][prow*64 + ((6 + hb) ^ sw)*8 + lo] = f2bf(e3 * inv);
    }
    s16x8 pf[2];
    #pragma unroll
    for (int ks = 0; ks < 2; ++ks)
      pf[ks] = *(const s16x8*)&Pl[w][(l & 15)*64 + ((ks*4 + (l >> 4)) ^ (l & 7))*8];
    f32x4 oc[4];
    #pragma unroll
    for (int ni = 0; ni < 4; ++ni) {
      f32x4 z; z[0]=0.f; z[1]=0.f; z[2]=0.f; z[3]=0.f;
      z = __builtin_amdgcn_mfma_f32_16x16x32_bf16(pf[0], vf[0][ni], z, 0, 0, 0);
      oc[ni] = __builtin_amdgcn_mfma_f32_16x16x32_bf16(pf[1], vf[1][ni], z, 0, 0, 0);
    }
    #pragma unroll
    for (int ni = 0; ni < 4; ++ni)
      #pragma unroll
      for (int r = 0; r < 4; ++r) {
        int row = r0 + (l >> 4)*4 + r;
        aout[(size_t)(b*NT + row)*ND + h*NHD + ni*16 + (l & 15)] = f2bf(oc[ni][r]);
      }
  }
}

extern "C" void kernel_launch(void* const* d_in, const int* in_sizes, int n_in,
                              void* d_out, int out_size, void* d_ws, size_t ws_size,
                              hipStream_t stream) {
  (void)in_sizes; (void)n_in; (void)out_size; (void)ws_size;
  const float* x  = (const float*)d_in[0];
  const float* Wq = (const float*)d_in[1];
  const float* Wk = (const float*)d_in[2];
  const float* Wv = (const float*)d_in[3];
  const float* Wo = (const float*)d_in[4];
  const float* wscore = (const float*)d_in[5];

  char* base = (char*)d_ws;
  ushort* xb     = (ushort*)(base + 0);           // 64 MiB  (reused as attn out)
  ushort* qb     = (ushort*)(base + 67108864);    // 64 MiB
  float*  scores = (float*) (base + 134217728);   // 2 MiB
  float*  u      = (float*) (base + 136314880);   // 64 KiB
  ushort* wqb    = (ushort*)(base + 136380416);   // 2 MiB
  ushort* wkb    = (ushort*)(base + 138477568);   // 2 MiB
  ushort* wvb    = (ushort*)(base + 140574720);   // 2 MiB
  ushort* wob    = (ushort*)(base + 142671872);   // 2 MiB
  int*    tidx   = (int*)   (base + 144769024);   // 16 KiB
  ushort* ksp    = (ushort*)(base + 144785408);   // 512 KiB
  ushort* vtsp   = (ushort*)(base + 145309696);   // 512 KiB
  ushort* aout   = xb;   // xb is dead after gemm_q + sparse_kv

  convert_w_kernel<<<dim3(4096), dim3(256), 0, stream>>>(Wq, Wk, Wv, Wo, wqb, wkb, wvb, wob);
  prep_u_kernel<<<dim3(64), dim3(256), 0, stream>>>(Wk, wscore, u);
  prep_x_kernel<<<dim3(1024), dim3(256), 0, stream>>>(x, u, xb, scores);
  topk_kernel<<<dim3(64), dim3(256), 0, stream>>>(scores, tidx);
  sparse_kv_kernel<<<dim3(64, 4), dim3(256), 0, stream>>>(xb, wkb, wvb, tidx, ksp, vtsp);
  gemm8_kernel<1><<<dim3(512), dim3(512), 0, stream>>>(xb, wqb, (void*)qb);
  attn_kernel<<<dim3(32, 64), dim3(256), 0, stream>>>(qb, ksp, vtsp, aout);
  gemm8_kernel<0><<<dim3(512), dim3(512), 0, stream>>>(aout, wob, d_out);
}